// Round 1
// baseline (1751.431 us; speedup 1.0000x reference)
//
#include <hip/hip_runtime.h>
#include <hip/hip_bf16.h>
#include <math.h>

#define N_NODES 50000
#define N_EDGES 800000
#define ET (N_EDGES + N_NODES)   // edges + self-loops
#define IN_DIM 128
#define HID 64
#define HEADS 4
#define C1 (HEADS * HID)         // 256
#define OUT_DIM 128
#define NEG_SLOPE 0.2f

// ---------- helpers ----------
__device__ __forceinline__ unsigned f2ord(float f) {
    unsigned u = __float_as_uint(f);
    return (u & 0x80000000u) ? ~u : (u | 0x80000000u);
}
__device__ __forceinline__ float ord2f(unsigned u) {
    return (u & 0x80000000u) ? __uint_as_float(u & 0x7FFFFFFFu) : __uint_as_float(~u);
}
__device__ __forceinline__ float leaky(float v) {
    return v > 0.0f ? v : NEG_SLOPE * v;
}

// ---------- GEMM1: h1[N,256] = x[N,128] @ W1[128,256] ----------
// block: 256 threads, 8 rows per block
__global__ void gemm1_kernel(const float* __restrict__ x, const float* __restrict__ W,
                             float* __restrict__ h) {
    __shared__ float xs[8][IN_DIM];
    const int row0 = blockIdx.x * 8;
    const int t = threadIdx.x;
    for (int i = t; i < 8 * IN_DIM; i += 256) {
        int r = i >> 7, c = i & 127;
        xs[r][c] = x[(row0 + r) * IN_DIM + c];
    }
    __syncthreads();
    float acc[8] = {0.f, 0.f, 0.f, 0.f, 0.f, 0.f, 0.f, 0.f};
    for (int k = 0; k < IN_DIM; ++k) {
        float w = W[k * C1 + t];
#pragma unroll
        for (int r = 0; r < 8; ++r) acc[r] += xs[r][k] * w;
    }
#pragma unroll
    for (int r = 0; r < 8; ++r) h[(row0 + r) * C1 + t] = acc[r];
}

// ---------- GEMM2: h2[N,128] = a[N,256] @ W2[256,128] ----------
// block: 128 threads, 8 rows per block
__global__ void gemm2_kernel(const float* __restrict__ a, const float* __restrict__ W,
                             float* __restrict__ h) {
    __shared__ float xs[8][C1];
    const int row0 = blockIdx.x * 8;
    const int t = threadIdx.x;
    for (int i = t; i < 8 * C1; i += 128) {
        int r = i >> 8, c = i & 255;
        xs[r][c] = a[(row0 + r) * C1 + c];
    }
    __syncthreads();
    float acc[8] = {0.f, 0.f, 0.f, 0.f, 0.f, 0.f, 0.f, 0.f};
    for (int k = 0; k < C1; ++k) {
        float w = W[k * OUT_DIM + t];
#pragma unroll
        for (int r = 0; r < 8; ++r) acc[r] += xs[r][k] * w;
    }
#pragma unroll
    for (int r = 0; r < 8; ++r) h[(row0 + r) * OUT_DIM + t] = acc[r];
}

// ---------- per-node attention dots, layer 1 ----------
// block: 256 threads = 4 waves, wave w handles head w. One node per block.
__global__ void attn1_kernel(const float* __restrict__ h1, const float* __restrict__ aw_src,
                             const float* __restrict__ aw_dst, float* __restrict__ as,
                             float* __restrict__ ad) {
    const int n = blockIdx.x;
    const int t = threadIdx.x;
    float hv = h1[n * C1 + t];
    float ps = hv * aw_src[t];
    float pd = hv * aw_dst[t];
#pragma unroll
    for (int o = 32; o > 0; o >>= 1) {
        ps += __shfl_down(ps, o);
        pd += __shfl_down(pd, o);
    }
    if ((t & 63) == 0) {
        as[n * HEADS + (t >> 6)] = ps;
        ad[n * HEADS + (t >> 6)] = pd;
    }
}

// ---------- per-node attention dots, layer 2 (single head, dim 128) ----------
__global__ void attn2_kernel(const float* __restrict__ h2, const float* __restrict__ aw_src,
                             const float* __restrict__ aw_dst, float* __restrict__ as,
                             float* __restrict__ ad) {
    __shared__ float ls[4];
    const int n = blockIdx.x;
    const int t = threadIdx.x;  // 128
    float hv = h2[n * OUT_DIM + t];
    float ps = hv * aw_src[t];
    float pd = hv * aw_dst[t];
#pragma unroll
    for (int o = 32; o > 0; o >>= 1) {
        ps += __shfl_down(ps, o);
        pd += __shfl_down(pd, o);
    }
    if ((t & 63) == 0) {
        ls[(t >> 6) * 2] = ps;
        ls[(t >> 6) * 2 + 1] = pd;
    }
    __syncthreads();
    if (t == 0) {
        as[n] = ls[0] + ls[2];
        ad[n] = ls[1] + ls[3];
    }
}

// ---------- edge segment-max, layer 1 (4 heads) ----------
__global__ void edge_max1_kernel(const int* __restrict__ src, const int* __restrict__ dst,
                                 const float* __restrict__ as, const float* __restrict__ ad,
                                 unsigned* __restrict__ m) {
    int i = blockIdx.x * blockDim.x + threadIdx.x;
    if (i >= ET) return;
    int s, d;
    if (i < N_EDGES) { s = src[i]; d = dst[i]; } else { s = d = i - N_EDGES; }
    float4 av = ((const float4*)as)[s];
    float4 dv = ((const float4*)ad)[d];
    atomicMax(&m[d * 4 + 0], f2ord(leaky(av.x + dv.x)));
    atomicMax(&m[d * 4 + 1], f2ord(leaky(av.y + dv.y)));
    atomicMax(&m[d * 4 + 2], f2ord(leaky(av.z + dv.z)));
    atomicMax(&m[d * 4 + 3], f2ord(leaky(av.w + dv.w)));
}

// ---------- edge exp + segment-sum, layer 1 ----------
__global__ void edge_exp1_kernel(const int* __restrict__ src, const int* __restrict__ dst,
                                 const float* __restrict__ as, const float* __restrict__ ad,
                                 const unsigned* __restrict__ m, float* __restrict__ e_exp,
                                 float* __restrict__ denom) {
    int i = blockIdx.x * blockDim.x + threadIdx.x;
    if (i >= ET) return;
    int s, d;
    if (i < N_EDGES) { s = src[i]; d = dst[i]; } else { s = d = i - N_EDGES; }
    float4 av = ((const float4*)as)[s];
    float4 dv = ((const float4*)ad)[d];
    float4 ex;
    ex.x = expf(leaky(av.x + dv.x) - ord2f(m[d * 4 + 0]));
    ex.y = expf(leaky(av.y + dv.y) - ord2f(m[d * 4 + 1]));
    ex.z = expf(leaky(av.z + dv.z) - ord2f(m[d * 4 + 2]));
    ex.w = expf(leaky(av.w + dv.w) - ord2f(m[d * 4 + 3]));
    ((float4*)e_exp)[i] = ex;
    atomicAdd(&denom[d * 4 + 0], ex.x);
    atomicAdd(&denom[d * 4 + 1], ex.y);
    atomicAdd(&denom[d * 4 + 2], ex.z);
    atomicAdd(&denom[d * 4 + 3], ex.w);
}

// ---------- edge aggregation, layer 1: one block (256 thr) per edge ----------
__global__ void aggregate1_kernel(const int* __restrict__ src, const int* __restrict__ dst,
                                  const float* __restrict__ h1, const float* __restrict__ e_exp,
                                  const float* __restrict__ denom, float* __restrict__ out1) {
    const int i = blockIdx.x;
    const int t = threadIdx.x;
    int s, d;
    if (i < N_EDGES) { s = src[i]; d = dst[i]; } else { s = d = i - N_EDGES; }
    const int h = t >> 6;
    float alpha = e_exp[i * 4 + h] / (denom[d * 4 + h] + 1e-16f);
    atomicAdd(&out1[d * C1 + t], h1[s * C1 + t] * alpha);
}

// ---------- bias + ELU in place ----------
__global__ void bias_elu_kernel(float* __restrict__ a, const float* __restrict__ b1) {
    const int total = N_NODES * C1;
    for (int idx = blockIdx.x * blockDim.x + threadIdx.x; idx < total;
         idx += gridDim.x * blockDim.x) {
        float v = a[idx] + b1[idx & 255];
        a[idx] = v > 0.0f ? v : expm1f(v);
    }
}

// ---------- edge segment-max, layer 2 (1 head) ----------
__global__ void edge_max2_kernel(const int* __restrict__ src, const int* __restrict__ dst,
                                 const float* __restrict__ as, const float* __restrict__ ad,
                                 unsigned* __restrict__ m) {
    int i = blockIdx.x * blockDim.x + threadIdx.x;
    if (i >= ET) return;
    int s, d;
    if (i < N_EDGES) { s = src[i]; d = dst[i]; } else { s = d = i - N_EDGES; }
    atomicMax(&m[d], f2ord(leaky(as[s] + ad[d])));
}

// ---------- edge exp + segment-sum, layer 2 ----------
__global__ void edge_exp2_kernel(const int* __restrict__ src, const int* __restrict__ dst,
                                 const float* __restrict__ as, const float* __restrict__ ad,
                                 const unsigned* __restrict__ m, float* __restrict__ e_exp,
                                 float* __restrict__ denom) {
    int i = blockIdx.x * blockDim.x + threadIdx.x;
    if (i >= ET) return;
    int s, d;
    if (i < N_EDGES) { s = src[i]; d = dst[i]; } else { s = d = i - N_EDGES; }
    float ex = expf(leaky(as[s] + ad[d]) - ord2f(m[d]));
    e_exp[i] = ex;
    atomicAdd(&denom[d], ex);
}

// ---------- edge aggregation, layer 2: one block (128 thr) per edge ----------
__global__ void aggregate2_kernel(const int* __restrict__ src, const int* __restrict__ dst,
                                  const float* __restrict__ h2, const float* __restrict__ e_exp,
                                  const float* __restrict__ denom, float* __restrict__ out) {
    const int i = blockIdx.x;
    const int t = threadIdx.x;
    int s, d;
    if (i < N_EDGES) { s = src[i]; d = dst[i]; } else { s = d = i - N_EDGES; }
    float alpha = e_exp[i] / (denom[d] + 1e-16f);
    atomicAdd(&out[d * OUT_DIM + t], h2[s * OUT_DIM + t] * alpha);
}

// ---------- bias + L2 normalize, in place on d_out ----------
__global__ void finalize_kernel(float* __restrict__ out, const float* __restrict__ b2) {
    __shared__ float sred[2];
    const int n = blockIdx.x;
    const int t = threadIdx.x;  // 128
    float v = out[n * OUT_DIM + t] + b2[t];
    float ss = v * v;
#pragma unroll
    for (int o = 32; o > 0; o >>= 1) ss += __shfl_down(ss, o);
    if ((t & 63) == 0) sred[t >> 6] = ss;
    __syncthreads();
    float nrm = sqrtf(sred[0] + sred[1]);
    float scale = 1.0f / fmaxf(nrm, 1e-12f);
    out[n * OUT_DIM + t] = v * scale;
}

extern "C" void kernel_launch(void* const* d_in, const int* in_sizes, int n_in,
                              void* d_out, int out_size, void* d_ws, size_t ws_size,
                              hipStream_t stream) {
    const float* x    = (const float*)d_in[0];
    const int*   edge = (const int*)d_in[1];
    const int*   src  = edge;
    const int*   dst  = edge + N_EDGES;
    const float* W1   = (const float*)d_in[2];
    const float* aw_s1 = (const float*)d_in[3];
    const float* aw_d1 = (const float*)d_in[4];
    const float* b1   = (const float*)d_in[5];
    const float* W2   = (const float*)d_in[6];
    const float* aw_s2 = (const float*)d_in[7];
    const float* aw_d2 = (const float*)d_in[8];
    const float* b2   = (const float*)d_in[9];
    float* out = (float*)d_out;

    // ---- workspace layout (120 MB peak, buffers reused across layers) ----
    char* ws = (char*)d_ws;
    size_t off = 0;
    float* h1    = (float*)(ws + off); off += (size_t)N_NODES * C1 * 4;      // 51.2 MB (reused as h2)
    float* out1  = (float*)(ws + off); off += (size_t)N_NODES * C1 * 4;      // 51.2 MB
    float* e_exp1 = (float*)(ws + off); off += (size_t)ET * 4 * 4;           // 13.6 MB (reused as e_exp2)
    float* as1   = (float*)(ws + off); off += (size_t)N_NODES * HEADS * 4;
    float* ad1   = (float*)(ws + off); off += (size_t)N_NODES * HEADS * 4;
    unsigned* m1 = (unsigned*)(ws + off); off += (size_t)N_NODES * HEADS * 4;
    float* den1  = (float*)(ws + off); off += (size_t)N_NODES * HEADS * 4;
    float* as2   = (float*)(ws + off); off += (size_t)N_NODES * 4;
    float* ad2   = (float*)(ws + off); off += (size_t)N_NODES * 4;
    unsigned* m2 = (unsigned*)(ws + off); off += (size_t)N_NODES * 4;
    float* den2  = (float*)(ws + off); off += (size_t)N_NODES * 4;
    float* h2    = h1;        // layer-1 projection dead after aggregate1
    float* e_exp2 = e_exp1;   // layer-1 edge exps dead after aggregate1

    // ---- zero-init scatter targets (ws/out are poisoned each call) ----
    hipMemsetAsync(m1,  0, (size_t)N_NODES * HEADS * 4, stream);  // ord(0)=neg-NaN key < any real key
    hipMemsetAsync(den1, 0, (size_t)N_NODES * HEADS * 4, stream);
    hipMemsetAsync(out1, 0, (size_t)N_NODES * C1 * 4, stream);
    hipMemsetAsync(m2,  0, (size_t)N_NODES * 4, stream);
    hipMemsetAsync(den2, 0, (size_t)N_NODES * 4, stream);
    hipMemsetAsync(out, 0, (size_t)N_NODES * OUT_DIM * 4, stream);

    const int egrid = (ET + 255) / 256;

    // ---- layer 1 ----
    gemm1_kernel<<<N_NODES / 8, 256, 0, stream>>>(x, W1, h1);
    attn1_kernel<<<N_NODES, 256, 0, stream>>>(h1, aw_s1, aw_d1, as1, ad1);
    edge_max1_kernel<<<egrid, 256, 0, stream>>>(src, dst, as1, ad1, m1);
    edge_exp1_kernel<<<egrid, 256, 0, stream>>>(src, dst, as1, ad1, m1, e_exp1, den1);
    aggregate1_kernel<<<ET, 256, 0, stream>>>(src, dst, h1, e_exp1, den1, out1);
    bias_elu_kernel<<<2048, 256, 0, stream>>>(out1, b1);

    // ---- layer 2 ----
    gemm2_kernel<<<N_NODES / 8, 128, 0, stream>>>(out1, W2, h2);
    attn2_kernel<<<N_NODES, 128, 0, stream>>>(h2, aw_s2, aw_d2, as2, ad2);
    edge_max2_kernel<<<egrid, 256, 0, stream>>>(src, dst, as2, ad2, m2);
    edge_exp2_kernel<<<egrid, 256, 0, stream>>>(src, dst, as2, ad2, m2, e_exp2, den2);
    aggregate2_kernel<<<ET, 128, 0, stream>>>(src, dst, h2, e_exp2, den2, out);

    // ---- epilogue: bias + row L2 normalize ----
    finalize_kernel<<<N_NODES, 128, 0, stream>>>(out, b2);
}

// Round 2
// 628.396 us; speedup vs baseline: 2.7871x; 2.7871x over previous
//
#include <hip/hip_runtime.h>
#include <math.h>

#define N_NODES 50000
#define N_EDGES 800000
#define ET (N_EDGES + N_NODES)   // edges + self-loops
#define IN_DIM 128
#define HID 64
#define HEADS 4
#define C1 (HEADS * HID)         // 256
#define OUT_DIM 128
#define NEG_SLOPE 0.2f
#define CAP 256                  // edges staged in LDS per chunk

__device__ __forceinline__ float leaky(float v) { return v > 0.0f ? v : NEG_SLOPE * v; }

// ================= CSR build (runs every call; edges constant but no static caching allowed) =================
__global__ void count_kernel(const int* __restrict__ dst, int* __restrict__ cnt) {
    int i = blockIdx.x * blockDim.x + threadIdx.x;
    if (i >= ET) return;
    int d = (i < N_EDGES) ? dst[i] : i - N_EDGES;
    atomicAdd(&cnt[d], 1);
}

// single-block scan with carry: rp[i+1] = inclusive sum, cursor[i] = exclusive sum
__global__ void scan_kernel(const int* __restrict__ cnt, int* __restrict__ rp,
                            int* __restrict__ cursor) {
    __shared__ int wsum[16];
    __shared__ int carry;
    const int t = threadIdx.x, lane = t & 63, wv = t >> 6;
    if (t == 0) { carry = 0; rp[0] = 0; }
    __syncthreads();
    for (int base = 0; base < N_NODES; base += 1024) {
        int idx = base + t;
        int v = (idx < N_NODES) ? cnt[idx] : 0;
        int sc = v;
#pragma unroll
        for (int o = 1; o < 64; o <<= 1) {
            int u = __shfl_up(sc, o);
            if (lane >= o) sc += u;
        }
        if (lane == 63) wsum[wv] = sc;
        __syncthreads();
        int woff = 0, tot = 0;
#pragma unroll
        for (int w = 0; w < 16; ++w) {
            int s = wsum[w];
            tot += s;
            if (w < wv) woff += s;
        }
        int inc = sc + woff + carry;
        if (idx < N_NODES) { rp[idx + 1] = inc; cursor[idx] = inc - v; }
        __syncthreads();
        if (t == 0) carry += tot;
        __syncthreads();
    }
}

__global__ void scatter_kernel(const int* __restrict__ src, const int* __restrict__ dst,
                               int* __restrict__ cursor, int* __restrict__ col_src) {
    int i = blockIdx.x * blockDim.x + threadIdx.x;
    if (i >= ET) return;
    int s, d;
    if (i < N_EDGES) { s = src[i]; d = dst[i]; } else { s = d = i - N_EDGES; }
    int pos = atomicAdd(&cursor[d], 1);
    col_src[pos] = s;
}

// ================= GEMM1 + fused attention dots (layer 1) =================
// block: 256 threads (t = output col, wave == head), 8 rows per block
__global__ void gemm1_attn1(const float* __restrict__ x, const float* __restrict__ W,
                            const float* __restrict__ aws, const float* __restrict__ awd,
                            float* __restrict__ h, float* __restrict__ as1,
                            float* __restrict__ ad1) {
    __shared__ float xs[8][IN_DIM];
    const int row0 = blockIdx.x * 8;
    const int t = threadIdx.x, lane = t & 63, wv = t >> 6;
    for (int i = t; i < 8 * IN_DIM; i += 256) {
        int r = i >> 7, c = i & 127;
        xs[r][c] = x[(row0 + r) * IN_DIM + c];
    }
    __syncthreads();
    float acc[8] = {0.f, 0.f, 0.f, 0.f, 0.f, 0.f, 0.f, 0.f};
    for (int k = 0; k < IN_DIM; ++k) {
        float w = W[k * C1 + t];
#pragma unroll
        for (int r = 0; r < 8; ++r) acc[r] += xs[r][k] * w;
    }
    float was = aws[t], wad = awd[t];
#pragma unroll
    for (int r = 0; r < 8; ++r) {
        h[(size_t)(row0 + r) * C1 + t] = acc[r];
        float ps = acc[r] * was, pd = acc[r] * wad;
#pragma unroll
        for (int o = 32; o > 0; o >>= 1) { ps += __shfl_down(ps, o); pd += __shfl_down(pd, o); }
        if (lane == 0) { as1[(row0 + r) * HEADS + wv] = ps; ad1[(row0 + r) * HEADS + wv] = pd; }
    }
}

// ================= GEMM2 + fused attention dots (layer 2, single head) =================
// block: 128 threads, 8 rows per block
__global__ void gemm2_attn2(const float* __restrict__ a, const float* __restrict__ W,
                            const float* __restrict__ aws, const float* __restrict__ awd,
                            float* __restrict__ h, float* __restrict__ as2,
                            float* __restrict__ ad2) {
    __shared__ float xs[8][C1];
    __shared__ float rs[2][8], rd[2][8];
    const int row0 = blockIdx.x * 8;
    const int t = threadIdx.x, lane = t & 63, wv = t >> 6;
    for (int i = t; i < 8 * C1; i += 128) {
        int r = i >> 8, c = i & 255;
        xs[r][c] = a[(size_t)(row0 + r) * C1 + c];
    }
    __syncthreads();
    float acc[8] = {0.f, 0.f, 0.f, 0.f, 0.f, 0.f, 0.f, 0.f};
    for (int k = 0; k < C1; ++k) {
        float w = W[k * OUT_DIM + t];
#pragma unroll
        for (int r = 0; r < 8; ++r) acc[r] += xs[r][k] * w;
    }
    float was = aws[t], wad = awd[t];
#pragma unroll
    for (int r = 0; r < 8; ++r) {
        h[(size_t)(row0 + r) * OUT_DIM + t] = acc[r];
        float ps = acc[r] * was, pd = acc[r] * wad;
#pragma unroll
        for (int o = 32; o > 0; o >>= 1) { ps += __shfl_down(ps, o); pd += __shfl_down(pd, o); }
        if (lane == 0) { rs[wv][r] = ps; rd[wv][r] = pd; }
    }
    __syncthreads();
    if (t < 8) as2[row0 + t] = rs[0][t] + rs[1][t];
    else if (t < 16) ad2[row0 + t - 8] = rd[0][t - 8] + rd[1][t - 8];
}

// ================= fused softmax + aggregate, layer 1 =================
// one block (256 thr) per destination node; thread t = feature t, head = t>>6
__global__ void aggregate1_fused(const int* __restrict__ rp, const int* __restrict__ cs,
                                 const float* __restrict__ h1, const float* __restrict__ as1,
                                 const float* __restrict__ ad1, const float* __restrict__ b1,
                                 float* __restrict__ out1) {
    __shared__ float red[4][4];       // [wave][head]
    __shared__ float alpha[CAP][5];   // stride-5 pad vs bank conflicts
    __shared__ int ssrc[CAP];
    const int d = blockIdx.x, t = threadIdx.x, lane = t & 63, wv = t >> 6;
    const int e0 = rp[d], deg = rp[d + 1] - e0;  // deg >= 1 (self-loop)
    const float4 adv = ((const float4*)ad1)[d];
    // --- phase A: per-head max over incoming edges ---
    float m0 = -INFINITY, m1 = -INFINITY, m2 = -INFINITY, m3 = -INFINITY;
    for (int j = t; j < deg; j += 256) {
        int s = cs[e0 + j];
        float4 av = ((const float4*)as1)[s];
        m0 = fmaxf(m0, leaky(av.x + adv.x));
        m1 = fmaxf(m1, leaky(av.y + adv.y));
        m2 = fmaxf(m2, leaky(av.z + adv.z));
        m3 = fmaxf(m3, leaky(av.w + adv.w));
    }
#pragma unroll
    for (int o = 32; o > 0; o >>= 1) {
        m0 = fmaxf(m0, __shfl_down(m0, o)); m1 = fmaxf(m1, __shfl_down(m1, o));
        m2 = fmaxf(m2, __shfl_down(m2, o)); m3 = fmaxf(m3, __shfl_down(m3, o));
    }
    if (lane == 0) { red[wv][0] = m0; red[wv][1] = m1; red[wv][2] = m2; red[wv][3] = m3; }
    __syncthreads();
    m0 = fmaxf(fmaxf(red[0][0], red[1][0]), fmaxf(red[2][0], red[3][0]));
    m1 = fmaxf(fmaxf(red[0][1], red[1][1]), fmaxf(red[2][1], red[3][1]));
    m2 = fmaxf(fmaxf(red[0][2], red[1][2]), fmaxf(red[2][2], red[3][2]));
    m3 = fmaxf(fmaxf(red[0][3], red[1][3]), fmaxf(red[2][3], red[3][3]));
    // --- phase B/C per chunk: stage exp weights in LDS, gather+accumulate rows ---
    float d0 = 0.f, d1 = 0.f, d2 = 0.f, d3 = 0.f, acc = 0.f;
    for (int c0 = 0; c0 < deg; c0 += CAP) {
        int clen = min(CAP, deg - c0);
        __syncthreads();
        for (int j = t; j < clen; j += 256) {
            int s = cs[e0 + c0 + j];
            float4 av = ((const float4*)as1)[s];
            float x0 = expf(leaky(av.x + adv.x) - m0);
            float x1 = expf(leaky(av.y + adv.y) - m1);
            float x2 = expf(leaky(av.z + adv.z) - m2);
            float x3 = expf(leaky(av.w + adv.w) - m3);
            alpha[j][0] = x0; alpha[j][1] = x1; alpha[j][2] = x2; alpha[j][3] = x3;
            ssrc[j] = s;
            d0 += x0; d1 += x1; d2 += x2; d3 += x3;
        }
        __syncthreads();
        for (int j = 0; j < clen; ++j)
            acc += h1[(size_t)ssrc[j] * C1 + t] * alpha[j][wv];
    }
    // --- reduce denominators, normalize, bias + ELU ---
#pragma unroll
    for (int o = 32; o > 0; o >>= 1) {
        d0 += __shfl_down(d0, o); d1 += __shfl_down(d1, o);
        d2 += __shfl_down(d2, o); d3 += __shfl_down(d3, o);
    }
    __syncthreads();
    if (lane == 0) { red[wv][0] = d0; red[wv][1] = d1; red[wv][2] = d2; red[wv][3] = d3; }
    __syncthreads();
    float den = red[0][wv] + red[1][wv] + red[2][wv] + red[3][wv];
    float v = acc / (den + 1e-16f) + b1[t];
    out1[(size_t)d * C1 + t] = v > 0.0f ? v : expm1f(v);
}

// ================= fused softmax + aggregate + bias + L2-normalize, layer 2 =================
// one block (128 thr) per destination node
__global__ void aggregate2_fused(const int* __restrict__ rp, const int* __restrict__ cs,
                                 const float* __restrict__ h2, const float* __restrict__ as2,
                                 const float* __restrict__ ad2, const float* __restrict__ b2,
                                 float* __restrict__ out) {
    __shared__ float red[2];
    __shared__ float red2[2];
    __shared__ float alpha[CAP];
    __shared__ int ssrc[CAP];
    const int d = blockIdx.x, t = threadIdx.x, lane = t & 63, wv = t >> 6;
    const int e0 = rp[d], deg = rp[d + 1] - e0;
    const float adv = ad2[d];
    float m = -INFINITY;
    for (int j = t; j < deg; j += 128) m = fmaxf(m, leaky(as2[cs[e0 + j]] + adv));
#pragma unroll
    for (int o = 32; o > 0; o >>= 1) m = fmaxf(m, __shfl_down(m, o));
    if (lane == 0) red[wv] = m;
    __syncthreads();
    m = fmaxf(red[0], red[1]);
    float ds = 0.f, acc = 0.f;
    for (int c0 = 0; c0 < deg; c0 += CAP) {
        int clen = min(CAP, deg - c0);
        __syncthreads();
        for (int j = t; j < clen; j += 128) {
            int s = cs[e0 + c0 + j];
            float ex = expf(leaky(as2[s] + adv) - m);
            alpha[j] = ex; ssrc[j] = s;
            ds += ex;
        }
        __syncthreads();
        for (int j = 0; j < clen; ++j)
            acc += h2[(size_t)ssrc[j] * OUT_DIM + t] * alpha[j];
    }
#pragma unroll
    for (int o = 32; o > 0; o >>= 1) ds += __shfl_down(ds, o);
    __syncthreads();
    if (lane == 0) red2[wv] = ds;
    __syncthreads();
    float den = red2[0] + red2[1];
    float v = acc / (den + 1e-16f) + b2[t];
    // row L2 norm
    float ss = v * v;
#pragma unroll
    for (int o = 32; o > 0; o >>= 1) ss += __shfl_down(ss, o);
    __syncthreads();
    if (lane == 0) red[wv] = ss;
    __syncthreads();
    float nrm = sqrtf(red[0] + red[1]);
    out[(size_t)d * OUT_DIM + t] = v / fmaxf(nrm, 1e-12f);
}

extern "C" void kernel_launch(void* const* d_in, const int* in_sizes, int n_in,
                              void* d_out, int out_size, void* d_ws, size_t ws_size,
                              hipStream_t stream) {
    const float* x     = (const float*)d_in[0];
    const int*   edge  = (const int*)d_in[1];
    const int*   src   = edge;
    const int*   dst   = edge + N_EDGES;
    const float* W1    = (const float*)d_in[2];
    const float* aw_s1 = (const float*)d_in[3];
    const float* aw_d1 = (const float*)d_in[4];
    const float* b1    = (const float*)d_in[5];
    const float* W2    = (const float*)d_in[6];
    const float* aw_s2 = (const float*)d_in[7];
    const float* aw_d2 = (const float*)d_in[8];
    const float* b2    = (const float*)d_in[9];
    float* out = (float*)d_out;

    // ---- workspace layout (aligned to 256 B) ----
    char* ws = (char*)d_ws;
    size_t off = 0;
    auto alloc = [&](size_t bytes) {
        void* p = ws + off;
        off += (bytes + 255) & ~(size_t)255;
        return p;
    };
    float* h1      = (float*)alloc((size_t)N_NODES * C1 * 4);   // 51.2 MB (reused as h2)
    float* out1    = (float*)alloc((size_t)N_NODES * C1 * 4);   // 51.2 MB
    int*   col_src = (int*)alloc((size_t)ET * 4);               // 3.4 MB
    int*   rp      = (int*)alloc((size_t)(N_NODES + 1) * 4);
    int*   cursor  = (int*)alloc((size_t)N_NODES * 4);
    int*   cnt     = (int*)alloc((size_t)N_NODES * 4);
    float* as1     = (float*)alloc((size_t)N_NODES * HEADS * 4);
    float* ad1     = (float*)alloc((size_t)N_NODES * HEADS * 4);
    float* as2     = (float*)alloc((size_t)N_NODES * 4);
    float* ad2     = (float*)alloc((size_t)N_NODES * 4);
    float* h2      = h1;  // layer-1 projection dead after aggregate1

    hipMemsetAsync(cnt, 0, (size_t)N_NODES * 4, stream);

    const int egrid = (ET + 255) / 256;

    // ---- CSR build (reused by both layers) ----
    count_kernel<<<egrid, 256, 0, stream>>>(dst, cnt);
    scan_kernel<<<1, 1024, 0, stream>>>(cnt, rp, cursor);
    scatter_kernel<<<egrid, 256, 0, stream>>>(src, dst, cursor, col_src);

    // ---- layer 1 ----
    gemm1_attn1<<<N_NODES / 8, 256, 0, stream>>>(x, W1, aw_s1, aw_d1, h1, as1, ad1);
    aggregate1_fused<<<N_NODES, 256, 0, stream>>>(rp, col_src, h1, as1, ad1, b1, out1);

    // ---- layer 2 ----
    gemm2_attn2<<<N_NODES / 8, 128, 0, stream>>>(out1, W2, aw_s2, aw_d2, h2, as2, ad2);
    aggregate2_fused<<<N_NODES, 128, 0, stream>>>(rp, col_src, h2, as2, ad2, b2, out);
}

// Round 3
// 504.113 us; speedup vs baseline: 3.4743x; 1.2465x over previous
//
#include <hip/hip_runtime.h>
#include <hip/hip_fp16.h>
#include <math.h>

#define N_NODES 50000
#define N_EDGES 800000
#define ET (N_EDGES + N_NODES)   // edges + self-loops
#define IN_DIM 128
#define HID 64
#define HEADS 4
#define C1 (HEADS * HID)         // 256
#define OUT_DIM 128
#define NEG_SLOPE 0.2f
#define CAP 256                  // edges staged in LDS per chunk

__device__ __forceinline__ float leaky(float v) { return v > 0.0f ? v : NEG_SLOPE * v; }
__device__ __forceinline__ float elu(float v) { return v > 0.0f ? v : expm1f(v); }

// ================= CSR build (runs every call) =================
__global__ void count_kernel(const int* __restrict__ dst, int* __restrict__ cnt) {
    int i = blockIdx.x * blockDim.x + threadIdx.x;
    if (i >= ET) return;
    int d = (i < N_EDGES) ? dst[i] : i - N_EDGES;
    atomicAdd(&cnt[d], 1);
}

__global__ void scan_kernel(const int* __restrict__ cnt, int* __restrict__ rp,
                            int* __restrict__ cursor) {
    __shared__ int wsum[16];
    __shared__ int carry;
    const int t = threadIdx.x, lane = t & 63, wv = t >> 6;
    if (t == 0) { carry = 0; rp[0] = 0; }
    __syncthreads();
    for (int base = 0; base < N_NODES; base += 1024) {
        int idx = base + t;
        int v = (idx < N_NODES) ? cnt[idx] : 0;
        int sc = v;
#pragma unroll
        for (int o = 1; o < 64; o <<= 1) {
            int u = __shfl_up(sc, o);
            if (lane >= o) sc += u;
        }
        if (lane == 63) wsum[wv] = sc;
        __syncthreads();
        int woff = 0, tot = 0;
#pragma unroll
        for (int w = 0; w < 16; ++w) {
            int s = wsum[w];
            tot += s;
            if (w < wv) woff += s;
        }
        int inc = sc + woff + carry;
        if (idx < N_NODES) { rp[idx + 1] = inc; cursor[idx] = inc - v; }
        __syncthreads();
        if (t == 0) carry += tot;
        __syncthreads();
    }
}

__global__ void scatter_kernel(const int* __restrict__ src, const int* __restrict__ dst,
                               int* __restrict__ cursor, int* __restrict__ col_src) {
    int i = blockIdx.x * blockDim.x + threadIdx.x;
    if (i >= ET) return;
    int s, d;
    if (i < N_EDGES) { s = src[i]; d = dst[i]; } else { s = d = i - N_EDGES; }
    int pos = atomicAdd(&cursor[d], 1);
    col_src[pos] = s;
}

// ================= GEMM1 + fused attention dots (layer 1) =================
// block: 256 threads (t = output col, wave == head), 8 rows per block; h written fp16
__global__ void gemm1_attn1(const float* __restrict__ x, const float* __restrict__ W,
                            const float* __restrict__ aws, const float* __restrict__ awd,
                            __half* __restrict__ h, float* __restrict__ as1,
                            float* __restrict__ ad1) {
    __shared__ float xs[8][IN_DIM];
    const int row0 = blockIdx.x * 8;
    const int t = threadIdx.x, lane = t & 63, wv = t >> 6;
    for (int i = t; i < 8 * IN_DIM; i += 256) {
        int r = i >> 7, c = i & 127;
        xs[r][c] = x[(row0 + r) * IN_DIM + c];
    }
    __syncthreads();
    float acc[8] = {0.f, 0.f, 0.f, 0.f, 0.f, 0.f, 0.f, 0.f};
    for (int k = 0; k < IN_DIM; ++k) {
        float w = W[k * C1 + t];
#pragma unroll
        for (int r = 0; r < 8; ++r) acc[r] += xs[r][k] * w;
    }
    float was = aws[t], wad = awd[t];
#pragma unroll
    for (int r = 0; r < 8; ++r) {
        h[(size_t)(row0 + r) * C1 + t] = __float2half(acc[r]);
        float ps = acc[r] * was, pd = acc[r] * wad;
#pragma unroll
        for (int o = 32; o > 0; o >>= 1) { ps += __shfl_down(ps, o); pd += __shfl_down(pd, o); }
        if (lane == 0) { as1[(row0 + r) * HEADS + wv] = ps; ad1[(row0 + r) * HEADS + wv] = pd; }
    }
}

// ================= GEMM2 + fused attention dots (layer 2, single head) =================
__global__ void gemm2_attn2(const float* __restrict__ a, const float* __restrict__ W,
                            const float* __restrict__ aws, const float* __restrict__ awd,
                            __half* __restrict__ h, float* __restrict__ as2,
                            float* __restrict__ ad2) {
    __shared__ float xs[8][C1];
    __shared__ float rs[2][8], rd[2][8];
    const int row0 = blockIdx.x * 8;
    const int t = threadIdx.x, lane = t & 63, wv = t >> 6;
    for (int i = t; i < 8 * C1; i += 128) {
        int r = i >> 8, c = i & 255;
        xs[r][c] = a[(size_t)(row0 + r) * C1 + c];
    }
    __syncthreads();
    float acc[8] = {0.f, 0.f, 0.f, 0.f, 0.f, 0.f, 0.f, 0.f};
    for (int k = 0; k < C1; ++k) {
        float w = W[k * OUT_DIM + t];
#pragma unroll
        for (int r = 0; r < 8; ++r) acc[r] += xs[r][k] * w;
    }
    float was = aws[t], wad = awd[t];
#pragma unroll
    for (int r = 0; r < 8; ++r) {
        h[(size_t)(row0 + r) * OUT_DIM + t] = __float2half(acc[r]);
        float ps = acc[r] * was, pd = acc[r] * wad;
#pragma unroll
        for (int o = 32; o > 0; o >>= 1) { ps += __shfl_down(ps, o); pd += __shfl_down(pd, o); }
        if (lane == 0) { rs[wv][r] = ps; rd[wv][r] = pd; }
    }
    __syncthreads();
    if (t < 8) as2[row0 + t] = rs[0][t] + rs[1][t];
    else if (t < 16) ad2[row0 + t - 8] = rd[0][t - 8] + rd[1][t - 8];
}

// ================= fused softmax + aggregate, layer 1 =================
// one block (128 thr) per destination node; thread t = features {2t,2t+1}, head = t>>5
__global__ void aggregate1_fused(const int* __restrict__ rp, const int* __restrict__ cs,
                                 const __half* __restrict__ h1h, const float* __restrict__ as1,
                                 const float* __restrict__ ad1, const float* __restrict__ b1,
                                 float* __restrict__ out1) {
    __shared__ float alpha[CAP][4];
    __shared__ int ssrc[CAP];
    __shared__ float redm[2][4], redd[2][4];
    const int d = blockIdx.x, t = threadIdx.x, lane = t & 63, wv = t >> 6;
    const int e0 = rp[d], deg = rp[d + 1] - e0;  // deg >= 1 (self-loop)
    const float4 adv = ((const float4*)ad1)[d];
    const int hd = t >> 5;
    // --- per-head max over incoming edges ---
    float m0 = -INFINITY, m1 = -INFINITY, m2 = -INFINITY, m3 = -INFINITY;
    for (int j = t; j < deg; j += 128) {
        float4 av = ((const float4*)as1)[cs[e0 + j]];
        m0 = fmaxf(m0, leaky(av.x + adv.x));
        m1 = fmaxf(m1, leaky(av.y + adv.y));
        m2 = fmaxf(m2, leaky(av.z + adv.z));
        m3 = fmaxf(m3, leaky(av.w + adv.w));
    }
#pragma unroll
    for (int o = 32; o > 0; o >>= 1) {
        m0 = fmaxf(m0, __shfl_down(m0, o)); m1 = fmaxf(m1, __shfl_down(m1, o));
        m2 = fmaxf(m2, __shfl_down(m2, o)); m3 = fmaxf(m3, __shfl_down(m3, o));
    }
    if (lane == 0) { redm[wv][0] = m0; redm[wv][1] = m1; redm[wv][2] = m2; redm[wv][3] = m3; }
    __syncthreads();
    m0 = fmaxf(redm[0][0], redm[1][0]);
    m1 = fmaxf(redm[0][1], redm[1][1]);
    m2 = fmaxf(redm[0][2], redm[1][2]);
    m3 = fmaxf(redm[0][3], redm[1][3]);
    // --- chunked: stage exp weights in LDS, gather fp16 rows, accumulate ---
    float d0 = 0.f, d1 = 0.f, d2 = 0.f, d3 = 0.f;
    float2 a0 = {0.f, 0.f}, a1 = {0.f, 0.f}, a2 = {0.f, 0.f}, a3 = {0.f, 0.f};
    const __half2* hb = (const __half2*)h1h;
    for (int c0 = 0; c0 < deg; c0 += CAP) {
        int clen = min(CAP, deg - c0);
        __syncthreads();
        for (int j = t; j < clen; j += 128) {
            int s = cs[e0 + c0 + j];
            float4 av = ((const float4*)as1)[s];
            float x0 = expf(leaky(av.x + adv.x) - m0);
            float x1 = expf(leaky(av.y + adv.y) - m1);
            float x2 = expf(leaky(av.z + adv.z) - m2);
            float x3 = expf(leaky(av.w + adv.w) - m3);
            *(float4*)&alpha[j][0] = make_float4(x0, x1, x2, x3);
            ssrc[j] = s;
            d0 += x0; d1 += x1; d2 += x2; d3 += x3;
        }
        __syncthreads();
        int j = 0;
        for (; j + 4 <= clen; j += 4) {
            int s0 = ssrc[j], s1 = ssrc[j + 1], s2 = ssrc[j + 2], s3 = ssrc[j + 3];
            __half2 v0 = hb[(size_t)s0 * 128 + t];
            __half2 v1 = hb[(size_t)s1 * 128 + t];
            __half2 v2 = hb[(size_t)s2 * 128 + t];
            __half2 v3 = hb[(size_t)s3 * 128 + t];
            float w0 = alpha[j][hd], w1 = alpha[j + 1][hd];
            float w2 = alpha[j + 2][hd], w3 = alpha[j + 3][hd];
            float2 f;
            f = __half22float2(v0); a0.x += f.x * w0; a0.y += f.y * w0;
            f = __half22float2(v1); a1.x += f.x * w1; a1.y += f.y * w1;
            f = __half22float2(v2); a2.x += f.x * w2; a2.y += f.y * w2;
            f = __half22float2(v3); a3.x += f.x * w3; a3.y += f.y * w3;
        }
        for (; j < clen; ++j) {
            __half2 v = hb[(size_t)ssrc[j] * 128 + t];
            float w = alpha[j][hd];
            float2 f = __half22float2(v);
            a0.x += f.x * w; a0.y += f.y * w;
        }
    }
    // --- reduce denominators, normalize, bias + ELU ---
#pragma unroll
    for (int o = 32; o > 0; o >>= 1) {
        d0 += __shfl_down(d0, o); d1 += __shfl_down(d1, o);
        d2 += __shfl_down(d2, o); d3 += __shfl_down(d3, o);
    }
    if (lane == 0) { redd[wv][0] = d0; redd[wv][1] = d1; redd[wv][2] = d2; redd[wv][3] = d3; }
    __syncthreads();
    float den = redd[0][hd] + redd[1][hd];
    float inv = 1.0f / (den + 1e-16f);
    float vx = (a0.x + a1.x + a2.x + a3.x) * inv + b1[2 * t];
    float vy = (a0.y + a1.y + a2.y + a3.y) * inv + b1[2 * t + 1];
    ((float2*)out1)[(size_t)d * 128 + t] = make_float2(elu(vx), elu(vy));
}

// ================= fused softmax + aggregate + bias + L2-normalize, layer 2 =================
// one block = one wave (64 thr) per destination node; thread t = features {2t,2t+1}
__global__ void aggregate2_fused(const int* __restrict__ rp, const int* __restrict__ cs,
                                 const __half* __restrict__ h2h, const float* __restrict__ as2,
                                 const float* __restrict__ ad2, const float* __restrict__ b2,
                                 float* __restrict__ out) {
    __shared__ float alpha[CAP];
    __shared__ int ssrc[CAP];
    const int d = blockIdx.x, t = threadIdx.x;  // 64
    const int e0 = rp[d], deg = rp[d + 1] - e0;
    const float adv = ad2[d];
    float m = -INFINITY;
    for (int j = t; j < deg; j += 64) m = fmaxf(m, leaky(as2[cs[e0 + j]] + adv));
#pragma unroll
    for (int o = 32; o > 0; o >>= 1) m = fmaxf(m, __shfl_down(m, o));
    m = __shfl(m, 0);
    float ds = 0.f;
    float2 a0 = {0.f, 0.f}, a1 = {0.f, 0.f}, a2 = {0.f, 0.f}, a3 = {0.f, 0.f};
    const __half2* hb = (const __half2*)h2h;
    for (int c0 = 0; c0 < deg; c0 += CAP) {
        int clen = min(CAP, deg - c0);
        __syncthreads();
        for (int j = t; j < clen; j += 64) {
            int s = cs[e0 + c0 + j];
            float ex = expf(leaky(as2[s] + adv) - m);
            alpha[j] = ex; ssrc[j] = s;
            ds += ex;
        }
        __syncthreads();
        int j = 0;
        for (; j + 4 <= clen; j += 4) {
            int s0 = ssrc[j], s1 = ssrc[j + 1], s2 = ssrc[j + 2], s3 = ssrc[j + 3];
            __half2 v0 = hb[(size_t)s0 * 64 + t];
            __half2 v1 = hb[(size_t)s1 * 64 + t];
            __half2 v2 = hb[(size_t)s2 * 64 + t];
            __half2 v3 = hb[(size_t)s3 * 64 + t];
            float w0 = alpha[j], w1 = alpha[j + 1], w2 = alpha[j + 2], w3 = alpha[j + 3];
            float2 f;
            f = __half22float2(v0); a0.x += f.x * w0; a0.y += f.y * w0;
            f = __half22float2(v1); a1.x += f.x * w1; a1.y += f.y * w1;
            f = __half22float2(v2); a2.x += f.x * w2; a2.y += f.y * w2;
            f = __half22float2(v3); a3.x += f.x * w3; a3.y += f.y * w3;
        }
        for (; j < clen; ++j) {
            __half2 v = hb[(size_t)ssrc[j] * 64 + t];
            float w = alpha[j];
            float2 f = __half22float2(v);
            a0.x += f.x * w; a0.y += f.y * w;
        }
    }
#pragma unroll
    for (int o = 32; o > 0; o >>= 1) ds += __shfl_down(ds, o);
    ds = __shfl(ds, 0);
    float inv = 1.0f / (ds + 1e-16f);
    float vx = (a0.x + a1.x + a2.x + a3.x) * inv + b2[2 * t];
    float vy = (a0.y + a1.y + a2.y + a3.y) * inv + b2[2 * t + 1];
    float ss = vx * vx + vy * vy;
#pragma unroll
    for (int o = 32; o > 0; o >>= 1) ss += __shfl_down(ss, o);
    ss = __shfl(ss, 0);
    float sc = 1.0f / fmaxf(sqrtf(ss), 1e-12f);
    ((float2*)out)[(size_t)d * 64 + t] = make_float2(vx * sc, vy * sc);
}

extern "C" void kernel_launch(void* const* d_in, const int* in_sizes, int n_in,
                              void* d_out, int out_size, void* d_ws, size_t ws_size,
                              hipStream_t stream) {
    const float* x     = (const float*)d_in[0];
    const int*   edge  = (const int*)d_in[1];
    const int*   src   = edge;
    const int*   dst   = edge + N_EDGES;
    const float* W1    = (const float*)d_in[2];
    const float* aw_s1 = (const float*)d_in[3];
    const float* aw_d1 = (const float*)d_in[4];
    const float* b1    = (const float*)d_in[5];
    const float* W2    = (const float*)d_in[6];
    const float* aw_s2 = (const float*)d_in[7];
    const float* aw_d2 = (const float*)d_in[8];
    const float* b2    = (const float*)d_in[9];
    float* out = (float*)d_out;

    // ---- workspace layout (aligned to 256 B) ----
    char* ws = (char*)d_ws;
    size_t off = 0;
    auto alloc = [&](size_t bytes) {
        void* p = ws + off;
        off += (bytes + 255) & ~(size_t)255;
        return p;
    };
    __half* h1h    = (__half*)alloc((size_t)N_NODES * C1 * 2);   // 25.6 MB (reused as h2h)
    float*  out1   = (float*)alloc((size_t)N_NODES * C1 * 4);    // 51.2 MB
    int*    col_src = (int*)alloc((size_t)ET * 4);               // 3.4 MB
    int*    rp     = (int*)alloc((size_t)(N_NODES + 1) * 4);
    int*    cursor = (int*)alloc((size_t)N_NODES * 4);
    int*    cnt    = (int*)alloc((size_t)N_NODES * 4);
    float*  as1    = (float*)alloc((size_t)N_NODES * HEADS * 4);
    float*  ad1    = (float*)alloc((size_t)N_NODES * HEADS * 4);
    float*  as2    = (float*)alloc((size_t)N_NODES * 4);
    float*  ad2    = (float*)alloc((size_t)N_NODES * 4);
    __half* h2h    = h1h;  // layer-1 projection dead after aggregate1

    hipMemsetAsync(cnt, 0, (size_t)N_NODES * 4, stream);

    const int egrid = (ET + 255) / 256;

    // ---- CSR build (reused by both layers) ----
    count_kernel<<<egrid, 256, 0, stream>>>(dst, cnt);
    scan_kernel<<<1, 1024, 0, stream>>>(cnt, rp, cursor);
    scatter_kernel<<<egrid, 256, 0, stream>>>(src, dst, cursor, col_src);

    // ---- layer 1 ----
    gemm1_attn1<<<N_NODES / 8, 256, 0, stream>>>(x, W1, aw_s1, aw_d1, h1h, as1, ad1);
    aggregate1_fused<<<N_NODES, 128, 0, stream>>>(rp, col_src, h1h, as1, ad1, b1, out1);

    // ---- layer 2 ----
    gemm2_attn2<<<N_NODES / 8, 128, 0, stream>>>(out1, W2, aw_s2, aw_d2, h2h, as2, ad2);
    aggregate2_fused<<<N_NODES, 64, 0, stream>>>(rp, col_src, h2h, as2, ad2, b2, out);
}

// Round 5
// 397.519 us; speedup vs baseline: 4.4059x; 1.2681x over previous
//
#include <hip/hip_runtime.h>
#include <hip/hip_fp16.h>
#include <math.h>

#define N_NODES 50000
#define N_EDGES 800000
#define ET (N_EDGES + N_NODES)   // edges + self-loops
#define IN_DIM 128
#define HID 64
#define HEADS 4
#define C1 (HEADS * HID)         // 256
#define OUT_DIM 128
#define NEG_SLOPE 0.2f
#define CAP 256                  // edges staged in LDS per chunk
#define MTILES 3125              // 50000 / 16 row-tiles
#define SCAN_B 1024
#define NSCB 49                  // ceil(50000/1024)

typedef _Float16 h8 __attribute__((ext_vector_type(8)));
typedef float f4 __attribute__((ext_vector_type(4)));

__device__ __forceinline__ float leaky(float v) { return v > 0.0f ? v : NEG_SLOPE * v; }
__device__ __forceinline__ float elu(float v) { return v > 0.0f ? v : expm1f(v); }

// ================= prep: fp32 -> fp16 conversions =================
__global__ void convert_x(const float* __restrict__ x, __half* __restrict__ xh) {
    const int total = N_NODES * IN_DIM / 4;
    for (int i = blockIdx.x * blockDim.x + threadIdx.x; i < total;
         i += gridDim.x * blockDim.x) {
        float4 v = ((const float4*)x)[i];
        ((__half2*)xh)[2 * i]     = __floats2half2_rn(v.x, v.y);
        ((__half2*)xh)[2 * i + 1] = __floats2half2_rn(v.z, v.w);
    }
}

// W1 [128][256] -> w1t [256][128] fp16 ; W2 [256][128] -> w2t [128][256] fp16
__global__ void prep_weights(const float* __restrict__ W1, const float* __restrict__ W2,
                             __half* __restrict__ w1t, __half* __restrict__ w2t) {
    int i = blockIdx.x * blockDim.x + threadIdx.x;
    if (i < IN_DIM * C1) {
        int k = i >> 8, n = i & 255;
        w1t[n * IN_DIM + k] = __float2half(W1[i]);
    }
    if (i < C1 * OUT_DIM) {
        int k = i >> 7, n = i & 127;
        w2t[n * C1 + k] = __float2half(W2[i]);
    }
}

// ================= CSR build =================
__global__ void count_kernel(const int* __restrict__ dst, int* __restrict__ cnt) {
    int i = blockIdx.x * blockDim.x + threadIdx.x;
    if (i >= ET) return;
    int d = (i < N_EDGES) ? dst[i] : i - N_EDGES;
    atomicAdd(&cnt[d], 1);
}

__global__ void scan_local(const int* __restrict__ cnt, int* __restrict__ lscan,
                           int* __restrict__ bsum) {
    __shared__ int wsum[16];
    const int t = threadIdx.x, lane = t & 63, wv = t >> 6;
    int idx = blockIdx.x * SCAN_B + t;
    int v = (idx < N_NODES) ? cnt[idx] : 0;
    int sc = v;
#pragma unroll
    for (int o = 1; o < 64; o <<= 1) {
        int u = __shfl_up(sc, o);
        if (lane >= o) sc += u;
    }
    if (lane == 63) wsum[wv] = sc;
    __syncthreads();
    if (t == 0) {
        int run = 0;
#pragma unroll
        for (int w = 0; w < 16; ++w) { int s = wsum[w]; wsum[w] = run; run += s; }
        bsum[blockIdx.x] = run;
    }
    __syncthreads();
    if (idx < N_NODES) lscan[idx] = sc + wsum[wv];  // inclusive within block
}

__global__ void scan_bsum(int* __restrict__ bsum) {  // 1 block, 64 thr
    const int t = threadIdx.x;
    int v = (t < NSCB) ? bsum[t] : 0;
    int sc = v;
#pragma unroll
    for (int o = 1; o < 64; o <<= 1) {
        int u = __shfl_up(sc, o);
        if (t >= o) sc += u;
    }
    if (t < NSCB) bsum[t] = sc - v;  // exclusive
}

__global__ void scan_final(const int* __restrict__ cnt, const int* __restrict__ lscan,
                           const int* __restrict__ bsum, int* __restrict__ rp,
                           int* __restrict__ cursor) {
    int idx = blockIdx.x * SCAN_B + threadIdx.x;
    if (idx == 0) rp[0] = 0;
    if (idx >= N_NODES) return;
    int inc = lscan[idx] + bsum[idx >> 10];
    rp[idx + 1] = inc;
    cursor[idx] = inc - cnt[idx];
}

__global__ void scatter_kernel(const int* __restrict__ src, const int* __restrict__ dst,
                               int* __restrict__ cursor, int* __restrict__ col_src) {
    int i = blockIdx.x * blockDim.x + threadIdx.x;
    if (i >= ET) return;
    int s, d;
    if (i < N_EDGES) { s = src[i]; d = dst[i]; } else { s = d = i - N_EDGES; }
    int pos = atomicAdd(&cursor[d], 1);
    col_src[pos] = s;
}

// ================= GEMM1 (MFMA fp16) + fused attention dots =================
__global__ __launch_bounds__(256) void gemm1_mfma(
        const __half* __restrict__ xh, const __half* __restrict__ w1t,
        const float* __restrict__ aws, const float* __restrict__ awd,
        __half* __restrict__ h, float* __restrict__ as1, float* __restrict__ ad1) {
    const int tile = blockIdx.x * 4 + (threadIdx.x >> 6);
    if (tile >= MTILES) return;
    const int lane = threadIdx.x & 63;
    const int m0 = tile * 16, lm = lane & 15, lq = lane >> 4;
    h8 afrag[4];
    const h8* arow = (const h8*)(xh + (size_t)(m0 + lm) * IN_DIM + lq * 8);
#pragma unroll
    for (int kt = 0; kt < 4; ++kt) afrag[kt] = arow[kt * 4];
    f4 acc[16];
#pragma unroll
    for (int nt = 0; nt < 16; ++nt) acc[nt] = (f4){0.f, 0.f, 0.f, 0.f};
#pragma unroll
    for (int nt = 0; nt < 16; ++nt) {
        const h8* brow = (const h8*)(w1t + (size_t)(nt * 16 + lm) * IN_DIM + lq * 8);
#pragma unroll
        for (int kt = 0; kt < 4; ++kt)
            acc[nt] = __builtin_amdgcn_mfma_f32_16x16x32_f16(afrag[kt], brow[kt * 4],
                                                             acc[nt], 0, 0, 0);
    }
    float sS[4][4] = {{0.f}}, sD[4][4] = {{0.f}};
#pragma unroll
    for (int nt = 0; nt < 16; ++nt) {
        int col = nt * 16 + lm;
        float wa = aws[col], wd = awd[col];
        int hd = nt >> 2;
#pragma unroll
        for (int r = 0; r < 4; ++r) {
            float v = acc[nt][r];
            h[(size_t)(m0 + lq * 4 + r) * C1 + col] = __float2half(v);
            sS[hd][r] += v * wa;
            sD[hd][r] += v * wd;
        }
    }
#pragma unroll
    for (int o = 1; o < 16; o <<= 1) {
#pragma unroll
        for (int hd = 0; hd < 4; ++hd)
#pragma unroll
            for (int r = 0; r < 4; ++r) {
                sS[hd][r] += __shfl_xor(sS[hd][r], o);
                sD[hd][r] += __shfl_xor(sD[hd][r], o);
            }
    }
    if (lm == 0) {
#pragma unroll
        for (int r = 0; r < 4; ++r) {
            int row = m0 + lq * 4 + r;
            ((float4*)as1)[row] = make_float4(sS[0][r], sS[1][r], sS[2][r], sS[3][r]);
            ((float4*)ad1)[row] = make_float4(sD[0][r], sD[1][r], sD[2][r], sD[3][r]);
        }
    }
}

// ================= GEMM2 (MFMA fp16) + fused attention dots (1 head) =================
__global__ __launch_bounds__(256) void gemm2_mfma(
        const __half* __restrict__ ah, const __half* __restrict__ w2t,
        const float* __restrict__ aws, const float* __restrict__ awd,
        __half* __restrict__ h, float* __restrict__ as2, float* __restrict__ ad2) {
    const int tile = blockIdx.x * 4 + (threadIdx.x >> 6);
    if (tile >= MTILES) return;
    const int lane = threadIdx.x & 63;
    const int m0 = tile * 16, lm = lane & 15, lq = lane >> 4;
    h8 afrag[8];
    const h8* arow = (const h8*)(ah + (size_t)(m0 + lm) * C1 + lq * 8);
#pragma unroll
    for (int kt = 0; kt < 8; ++kt) afrag[kt] = arow[kt * 4];
    f4 acc[8];
#pragma unroll
    for (int nt = 0; nt < 8; ++nt) acc[nt] = (f4){0.f, 0.f, 0.f, 0.f};
#pragma unroll
    for (int nt = 0; nt < 8; ++nt) {
        const h8* brow = (const h8*)(w2t + (size_t)(nt * 16 + lm) * C1 + lq * 8);
#pragma unroll
        for (int kt = 0; kt < 8; ++kt)
            acc[nt] = __builtin_amdgcn_mfma_f32_16x16x32_f16(afrag[kt], brow[kt * 4],
                                                             acc[nt], 0, 0, 0);
    }
    float sS[4] = {0.f, 0.f, 0.f, 0.f}, sD[4] = {0.f, 0.f, 0.f, 0.f};
#pragma unroll
    for (int nt = 0; nt < 8; ++nt) {
        int col = nt * 16 + lm;
        float wa = aws[col], wd = awd[col];
#pragma unroll
        for (int r = 0; r < 4; ++r) {
            float v = acc[nt][r];
            h[(size_t)(m0 + lq * 4 + r) * OUT_DIM + col] = __float2half(v);
            sS[r] += v * wa;
            sD[r] += v * wd;
        }
    }
#pragma unroll
    for (int o = 1; o < 16; o <<= 1) {
#pragma unroll
        for (int r = 0; r < 4; ++r) {
            sS[r] += __shfl_xor(sS[r], o);
            sD[r] += __shfl_xor(sD[r], o);
        }
    }
    if (lm == 0) {
#pragma unroll
        for (int r = 0; r < 4; ++r) {
            int row = m0 + lq * 4 + r;
            as2[row] = sS[r];
            ad2[row] = sD[r];
        }
    }
}

// ================= fused softmax + aggregate, layer 1 (out fp16) =================
__global__ void aggregate1_fused(const int* __restrict__ rp, const int* __restrict__ cs,
                                 const __half* __restrict__ h1h, const float* __restrict__ as1,
                                 const float* __restrict__ ad1, const float* __restrict__ b1,
                                 __half* __restrict__ out1h) {
    __shared__ float alpha[CAP][4];
    __shared__ int ssrc[CAP];
    __shared__ float redm[2][4], redd[2][4];
    const int d = blockIdx.x, t = threadIdx.x, lane = t & 63, wv = t >> 6;
    const int e0 = rp[d], deg = rp[d + 1] - e0;  // deg >= 1 (self-loop)
    const float4 adv = ((const float4*)ad1)[d];
    const int hd = t >> 5;
    float m0 = -INFINITY, m1 = -INFINITY, m2 = -INFINITY, m3 = -INFINITY;
    for (int j = t; j < deg; j += 128) {
        float4 av = ((const float4*)as1)[cs[e0 + j]];
        m0 = fmaxf(m0, leaky(av.x + adv.x));
        m1 = fmaxf(m1, leaky(av.y + adv.y));
        m2 = fmaxf(m2, leaky(av.z + adv.z));
        m3 = fmaxf(m3, leaky(av.w + adv.w));
    }
#pragma unroll
    for (int o = 32; o > 0; o >>= 1) {
        m0 = fmaxf(m0, __shfl_down(m0, o)); m1 = fmaxf(m1, __shfl_down(m1, o));
        m2 = fmaxf(m2, __shfl_down(m2, o)); m3 = fmaxf(m3, __shfl_down(m3, o));
    }
    if (lane == 0) { redm[wv][0] = m0; redm[wv][1] = m1; redm[wv][2] = m2; redm[wv][3] = m3; }
    __syncthreads();
    m0 = fmaxf(redm[0][0], redm[1][0]);
    m1 = fmaxf(redm[0][1], redm[1][1]);
    m2 = fmaxf(redm[0][2], redm[1][2]);
    m3 = fmaxf(redm[0][3], redm[1][3]);
    float d0 = 0.f, d1 = 0.f, d2 = 0.f, d3 = 0.f;
    float2 a0 = {0.f, 0.f}, a1 = {0.f, 0.f}, a2 = {0.f, 0.f}, a3 = {0.f, 0.f};
    const __half2* hb = (const __half2*)h1h;
    for (int c0 = 0; c0 < deg; c0 += CAP) {
        int clen = min(CAP, deg - c0);
        __syncthreads();
        for (int j = t; j < clen; j += 128) {
            int s = cs[e0 + c0 + j];
            float4 av = ((const float4*)as1)[s];
            float x0 = expf(leaky(av.x + adv.x) - m0);
            float x1 = expf(leaky(av.y + adv.y) - m1);
            float x2 = expf(leaky(av.z + adv.z) - m2);
            float x3 = expf(leaky(av.w + adv.w) - m3);
            *(float4*)&alpha[j][0] = make_float4(x0, x1, x2, x3);
            ssrc[j] = s;
            d0 += x0; d1 += x1; d2 += x2; d3 += x3;
        }
        __syncthreads();
        int j = 0;
        for (; j + 4 <= clen; j += 4) {
            int s0 = ssrc[j], s1 = ssrc[j + 1], s2 = ssrc[j + 2], s3 = ssrc[j + 3];
            __half2 v0 = hb[(size_t)s0 * 128 + t];
            __half2 v1 = hb[(size_t)s1 * 128 + t];
            __half2 v2 = hb[(size_t)s2 * 128 + t];
            __half2 v3 = hb[(size_t)s3 * 128 + t];
            float w0 = alpha[j][hd], w1 = alpha[j + 1][hd];
            float w2 = alpha[j + 2][hd], w3 = alpha[j + 3][hd];
            float2 f;
            f = __half22float2(v0); a0.x += f.x * w0; a0.y += f.y * w0;
            f = __half22float2(v1); a1.x += f.x * w1; a1.y += f.y * w1;
            f = __half22float2(v2); a2.x += f.x * w2; a2.y += f.y * w2;
            f = __half22float2(v3); a3.x += f.x * w3; a3.y += f.y * w3;
        }
        for (; j < clen; ++j) {
            __half2 v = hb[(size_t)ssrc[j] * 128 + t];
            float w = alpha[j][hd];
            float2 f = __half22float2(v);
            a0.x += f.x * w; a0.y += f.y * w;
        }
    }
#pragma unroll
    for (int o = 32; o > 0; o >>= 1) {
        d0 += __shfl_down(d0, o); d1 += __shfl_down(d1, o);
        d2 += __shfl_down(d2, o); d3 += __shfl_down(d3, o);
    }
    if (lane == 0) { redd[wv][0] = d0; redd[wv][1] = d1; redd[wv][2] = d2; redd[wv][3] = d3; }
    __syncthreads();
    float den = redd[0][hd] + redd[1][hd];
    float inv = 1.0f / (den + 1e-16f);
    float vx = (a0.x + a1.x + a2.x + a3.x) * inv + b1[2 * t];
    float vy = (a0.y + a1.y + a2.y + a3.y) * inv + b1[2 * t + 1];
    ((__half2*)out1h)[(size_t)d * 128 + t] = __floats2half2_rn(elu(vx), elu(vy));
}

// ================= fused softmax + aggregate + bias + L2-normalize, layer 2 =================
__global__ void aggregate2_fused(const int* __restrict__ rp, const int* __restrict__ cs,
                                 const __half* __restrict__ h2h, const float* __restrict__ as2,
                                 const float* __restrict__ ad2, const float* __restrict__ b2,
                                 float* __restrict__ out) {
    __shared__ float alpha[CAP];
    __shared__ int ssrc[CAP];
    const int d = blockIdx.x, t = threadIdx.x;  // 64
    const int e0 = rp[d], deg = rp[d + 1] - e0;
    const float adv = ad2[d];
    float m = -INFINITY;
    for (int j = t; j < deg; j += 64) m = fmaxf(m, leaky(as2[cs[e0 + j]] + adv));
#pragma unroll
    for (int o = 32; o > 0; o >>= 1) m = fmaxf(m, __shfl_down(m, o));
    m = __shfl(m, 0);
    float ds = 0.f;
    float2 a0 = {0.f, 0.f}, a1 = {0.f, 0.f}, a2 = {0.f, 0.f}, a3 = {0.f, 0.f};
    const __half2* hb = (const __half2*)h2h;
    for (int c0 = 0; c0 < deg; c0 += CAP) {
        int clen = min(CAP, deg - c0);
        __syncthreads();
        for (int j = t; j < clen; j += 64) {
            int s = cs[e0 + c0 + j];
            float ex = expf(leaky(as2[s] + adv) - m);
            alpha[j] = ex; ssrc[j] = s;
            ds += ex;
        }
        __syncthreads();
        int j = 0;
        for (; j + 4 <= clen; j += 4) {
            int s0 = ssrc[j], s1 = ssrc[j + 1], s2 = ssrc[j + 2], s3 = ssrc[j + 3];
            __half2 v0 = hb[(size_t)s0 * 64 + t];
            __half2 v1 = hb[(size_t)s1 * 64 + t];
            __half2 v2 = hb[(size_t)s2 * 64 + t];
            __half2 v3 = hb[(size_t)s3 * 64 + t];
            float w0 = alpha[j], w1 = alpha[j + 1], w2 = alpha[j + 2], w3 = alpha[j + 3];
            float2 f;
            f = __half22float2(v0); a0.x += f.x * w0; a0.y += f.y * w0;
            f = __half22float2(v1); a1.x += f.x * w1; a1.y += f.y * w1;
            f = __half22float2(v2); a2.x += f.x * w2; a2.y += f.y * w2;
            f = __half22float2(v3); a3.x += f.x * w3; a3.y += f.y * w3;
        }
        for (; j < clen; ++j) {
            __half2 v = hb[(size_t)ssrc[j] * 64 + t];
            float w = alpha[j];
            float2 f = __half22float2(v);
            a0.x += f.x * w; a0.y += f.y * w;
        }
    }
#pragma unroll
    for (int o = 32; o > 0; o >>= 1) ds += __shfl_down(ds, o);
    ds = __shfl(ds, 0);
    float inv = 1.0f / (ds + 1e-16f);
    float vx = (a0.x + a1.x + a2.x + a3.x) * inv + b2[2 * t];
    float vy = (a0.y + a1.y + a2.y + a3.y) * inv + b2[2 * t + 1];
    float ss = vx * vx + vy * vy;
#pragma unroll
    for (int o = 32; o > 0; o >>= 1) ss += __shfl_down(ss, o);
    ss = __shfl(ss, 0);
    float sc = 1.0f / fmaxf(sqrtf(ss), 1e-12f);
    ((float2*)out)[(size_t)d * 64 + t] = make_float2(vx * sc, vy * sc);
}

extern "C" void kernel_launch(void* const* d_in, const int* in_sizes, int n_in,
                              void* d_out, int out_size, void* d_ws, size_t ws_size,
                              hipStream_t stream) {
    const float* x     = (const float*)d_in[0];
    const int*   edge  = (const int*)d_in[1];
    const int*   src   = edge;
    const int*   dst   = edge + N_EDGES;
    const float* W1    = (const float*)d_in[2];
    const float* aw_s1 = (const float*)d_in[3];
    const float* aw_d1 = (const float*)d_in[4];
    const float* b1    = (const float*)d_in[5];
    const float* W2    = (const float*)d_in[6];
    const float* aw_s2 = (const float*)d_in[7];
    const float* aw_d2 = (const float*)d_in[8];
    const float* b2    = (const float*)d_in[9];
    float* out = (float*)d_out;

    // ---- workspace layout: small control buffers first, big streams last ----
    char* ws = (char*)d_ws;
    size_t off = 0;
    auto alloc = [&](size_t bytes) {
        void* p = ws + off;
        off += (bytes + 255) & ~(size_t)255;
        return p;
    };
    int*    col_src = (int*)alloc((size_t)ET * 4);                  // 3.4 MB
    int*    rp     = (int*)alloc((size_t)(N_NODES + 1) * 4);
    int*    cursor = (int*)alloc((size_t)N_NODES * 4);
    int*    cnt    = (int*)alloc((size_t)N_NODES * 4);
    int*    lscan  = (int*)alloc((size_t)NSCB * SCAN_B * 4);
    int*    bsum   = (int*)alloc((size_t)NSCB * 4);
    float*  as1    = (float*)alloc((size_t)N_NODES * HEADS * 4);
    float*  ad1    = (float*)alloc((size_t)N_NODES * HEADS * 4);
    float*  as2    = (float*)alloc((size_t)N_NODES * 4);
    float*  ad2    = (float*)alloc((size_t)N_NODES * 4);
    __half* w1t    = (__half*)alloc((size_t)IN_DIM * C1 * 2);
    __half* w2t    = (__half*)alloc((size_t)C1 * OUT_DIM * 2);
    __half* xh     = (__half*)alloc((size_t)N_NODES * IN_DIM * 2);  // 12.8 MB
    __half* h1h    = (__half*)alloc((size_t)N_NODES * C1 * 2);      // 25.6 MB (reused as h2h)
    __half* out1h  = (__half*)alloc((size_t)N_NODES * C1 * 2);      // 25.6 MB
    __half* h2h    = h1h;  // layer-1 projection dead after aggregate1
    const size_t ws_used = off;

    // Reproduce call-1 initial state every call: zero the entire used workspace
    // and d_out (harness poisons both with 0xAA before timed launches).
    hipMemsetAsync(d_ws, 0, ws_used, stream);
    hipMemsetAsync(d_out, 0, (size_t)out_size * 4, stream);

    const int egrid = (ET + 255) / 256;

    // ---- prep + CSR build ----
    convert_x<<<2048, 256, 0, stream>>>(x, xh);
    prep_weights<<<128, 256, 0, stream>>>(W1, W2, w1t, w2t);
    count_kernel<<<egrid, 256, 0, stream>>>(dst, cnt);
    scan_local<<<NSCB, SCAN_B, 0, stream>>>(cnt, lscan, bsum);
    scan_bsum<<<1, 64, 0, stream>>>(bsum);
    scan_final<<<NSCB, SCAN_B, 0, stream>>>(cnt, lscan, bsum, rp, cursor);
    scatter_kernel<<<egrid, 256, 0, stream>>>(src, dst, cursor, col_src);

    // ---- layer 1 ----
    gemm1_mfma<<<(MTILES + 3) / 4, 256, 0, stream>>>(xh, w1t, aw_s1, aw_d1, h1h, as1, ad1);
    aggregate1_fused<<<N_NODES, 128, 0, stream>>>(rp, col_src, h1h, as1, ad1, b1, out1h);

    // ---- layer 2 ----
    gemm2_mfma<<<(MTILES + 3) / 4, 256, 0, stream>>>(out1h, w2t, aw_s2, aw_d2, h2h, as2, ad2);
    aggregate2_fused<<<N_NODES, 64, 0, stream>>>(rp, col_src, h2h, as2, ad2, b2, out);
}

// Round 6
// 383.758 us; speedup vs baseline: 4.5639x; 1.0359x over previous
//
#include <hip/hip_runtime.h>
#include <hip/hip_fp16.h>
#include <math.h>

#define N_NODES 50000
#define N_EDGES 800000
#define ET (N_EDGES + N_NODES)   // edges + self-loops
#define IN_DIM 128
#define HID 64
#define HEADS 4
#define C1 (HEADS * HID)         // 256
#define OUT_DIM 128
#define NEG_SLOPE 0.2f
#define MTILES 3125              // 50000 / 16 row-tiles
#define SCAN_B 1024
#define NSCB 49                  // ceil(50000/1024)

typedef _Float16 h8 __attribute__((ext_vector_type(8)));
typedef _Float16 h4 __attribute__((ext_vector_type(4)));
typedef float f4 __attribute__((ext_vector_type(4)));

__device__ __forceinline__ float leaky(float v) { return v > 0.0f ? v : NEG_SLOPE * v; }
__device__ __forceinline__ float elu(float v) { return v > 0.0f ? v : expm1f(v); }
__device__ __forceinline__ float rl_f(float v, int l) {
    return __int_as_float(__builtin_amdgcn_readlane(__float_as_int(v), l));
}

// ================= prep: fp32 -> fp16 conversions =================
__global__ void convert_x(const float* __restrict__ x, __half* __restrict__ xh) {
    const int total = N_NODES * IN_DIM / 4;
    for (int i = blockIdx.x * blockDim.x + threadIdx.x; i < total;
         i += gridDim.x * blockDim.x) {
        float4 v = ((const float4*)x)[i];
        ((__half2*)xh)[2 * i]     = __floats2half2_rn(v.x, v.y);
        ((__half2*)xh)[2 * i + 1] = __floats2half2_rn(v.z, v.w);
    }
}

// W1 [128][256] -> w1t [256][128] fp16 ; W2 [256][128] -> w2t [128][256] fp16
__global__ void prep_weights(const float* __restrict__ W1, const float* __restrict__ W2,
                             __half* __restrict__ w1t, __half* __restrict__ w2t) {
    int i = blockIdx.x * blockDim.x + threadIdx.x;
    if (i < IN_DIM * C1) {
        int k = i >> 8, n = i & 255;
        w1t[n * IN_DIM + k] = __float2half(W1[i]);
    }
    if (i < C1 * OUT_DIM) {
        int k = i >> 7, n = i & 127;
        w2t[n * C1 + k] = __float2half(W2[i]);
    }
}

// ================= CSR build =================
__global__ void count_kernel(const int* __restrict__ dst, int* __restrict__ cnt) {
    int i = blockIdx.x * blockDim.x + threadIdx.x;
    if (i >= ET) return;
    int d = (i < N_EDGES) ? dst[i] : i - N_EDGES;
    atomicAdd(&cnt[d], 1);
}

__global__ void scan_local(const int* __restrict__ cnt, int* __restrict__ lscan,
                           int* __restrict__ bsum) {
    __shared__ int wsum[16];
    const int t = threadIdx.x, lane = t & 63, wv = t >> 6;
    int idx = blockIdx.x * SCAN_B + t;
    int v = (idx < N_NODES) ? cnt[idx] : 0;
    int sc = v;
#pragma unroll
    for (int o = 1; o < 64; o <<= 1) {
        int u = __shfl_up(sc, o);
        if (lane >= o) sc += u;
    }
    if (lane == 63) wsum[wv] = sc;
    __syncthreads();
    if (t == 0) {
        int run = 0;
#pragma unroll
        for (int w = 0; w < 16; ++w) { int s = wsum[w]; wsum[w] = run; run += s; }
        bsum[blockIdx.x] = run;
    }
    __syncthreads();
    if (idx < N_NODES) lscan[idx] = sc + wsum[wv];  // inclusive within block
}

__global__ void scan_bsum(int* __restrict__ bsum) {  // 1 block, 64 thr
    const int t = threadIdx.x;
    int v = (t < NSCB) ? bsum[t] : 0;
    int sc = v;
#pragma unroll
    for (int o = 1; o < 64; o <<= 1) {
        int u = __shfl_up(sc, o);
        if (t >= o) sc += u;
    }
    if (t < NSCB) bsum[t] = sc - v;  // exclusive
}

__global__ void scan_final(const int* __restrict__ cnt, const int* __restrict__ lscan,
                           const int* __restrict__ bsum, int* __restrict__ rp,
                           int* __restrict__ cursor) {
    int idx = blockIdx.x * SCAN_B + threadIdx.x;
    if (idx == 0) rp[0] = 0;
    if (idx >= N_NODES) return;
    int inc = lscan[idx] + bsum[idx >> 10];
    rp[idx + 1] = inc;
    cursor[idx] = inc - cnt[idx];
}

__global__ void scatter_kernel(const int* __restrict__ src, const int* __restrict__ dst,
                               int* __restrict__ cursor, int* __restrict__ col_src) {
    int i = blockIdx.x * blockDim.x + threadIdx.x;
    if (i >= ET) return;
    int s, d;
    if (i < N_EDGES) { s = src[i]; d = dst[i]; } else { s = d = i - N_EDGES; }
    int pos = atomicAdd(&cursor[d], 1);
    col_src[pos] = s;
}

// ================= GEMM1 (MFMA fp16) + fused attention dots =================
__global__ __launch_bounds__(256) void gemm1_mfma(
        const __half* __restrict__ xh, const __half* __restrict__ w1t,
        const float* __restrict__ aws, const float* __restrict__ awd,
        __half* __restrict__ h, float* __restrict__ as1, float* __restrict__ ad1) {
    const int tile = blockIdx.x * 4 + (threadIdx.x >> 6);
    if (tile >= MTILES) return;
    const int lane = threadIdx.x & 63;
    const int m0 = tile * 16, lm = lane & 15, lq = lane >> 4;
    h8 afrag[4];
    const h8* arow = (const h8*)(xh + (size_t)(m0 + lm) * IN_DIM + lq * 8);
#pragma unroll
    for (int kt = 0; kt < 4; ++kt) afrag[kt] = arow[kt * 4];
    f4 acc[16];
#pragma unroll
    for (int nt = 0; nt < 16; ++nt) acc[nt] = (f4){0.f, 0.f, 0.f, 0.f};
#pragma unroll
    for (int nt = 0; nt < 16; ++nt) {
        const h8* brow = (const h8*)(w1t + (size_t)(nt * 16 + lm) * IN_DIM + lq * 8);
#pragma unroll
        for (int kt = 0; kt < 4; ++kt)
            acc[nt] = __builtin_amdgcn_mfma_f32_16x16x32_f16(afrag[kt], brow[kt * 4],
                                                             acc[nt], 0, 0, 0);
    }
    float sS[4][4] = {{0.f}}, sD[4][4] = {{0.f}};
#pragma unroll
    for (int nt = 0; nt < 16; ++nt) {
        int col = nt * 16 + lm;
        float wa = aws[col], wd = awd[col];
        int hd = nt >> 2;
#pragma unroll
        for (int r = 0; r < 4; ++r) {
            float v = acc[nt][r];
            h[(size_t)(m0 + lq * 4 + r) * C1 + col] = __float2half(v);
            sS[hd][r] += v * wa;
            sD[hd][r] += v * wd;
        }
    }
#pragma unroll
    for (int o = 1; o < 16; o <<= 1) {
#pragma unroll
        for (int hd = 0; hd < 4; ++hd)
#pragma unroll
            for (int r = 0; r < 4; ++r) {
                sS[hd][r] += __shfl_xor(sS[hd][r], o);
                sD[hd][r] += __shfl_xor(sD[hd][r], o);
            }
    }
    if (lm == 0) {
#pragma unroll
        for (int r = 0; r < 4; ++r) {
            int row = m0 + lq * 4 + r;
            ((float4*)as1)[row] = make_float4(sS[0][r], sS[1][r], sS[2][r], sS[3][r]);
            ((float4*)ad1)[row] = make_float4(sD[0][r], sD[1][r], sD[2][r], sD[3][r]);
        }
    }
}

// ================= GEMM2 (MFMA fp16) + fused attention dots (1 head) =================
__global__ __launch_bounds__(256) void gemm2_mfma(
        const __half* __restrict__ ah, const __half* __restrict__ w2t,
        const float* __restrict__ aws, const float* __restrict__ awd,
        __half* __restrict__ h, float* __restrict__ as2, float* __restrict__ ad2) {
    const int tile = blockIdx.x * 4 + (threadIdx.x >> 6);
    if (tile >= MTILES) return;
    const int lane = threadIdx.x & 63;
    const int m0 = tile * 16, lm = lane & 15, lq = lane >> 4;
    h8 afrag[8];
    const h8* arow = (const h8*)(ah + (size_t)(m0 + lm) * C1 + lq * 8);
#pragma unroll
    for (int kt = 0; kt < 8; ++kt) afrag[kt] = arow[kt * 4];
    f4 acc[8];
#pragma unroll
    for (int nt = 0; nt < 8; ++nt) acc[nt] = (f4){0.f, 0.f, 0.f, 0.f};
#pragma unroll
    for (int nt = 0; nt < 8; ++nt) {
        const h8* brow = (const h8*)(w2t + (size_t)(nt * 16 + lm) * C1 + lq * 8);
#pragma unroll
        for (int kt = 0; kt < 8; ++kt)
            acc[nt] = __builtin_amdgcn_mfma_f32_16x16x32_f16(afrag[kt], brow[kt * 4],
                                                             acc[nt], 0, 0, 0);
    }
    float sS[4] = {0.f, 0.f, 0.f, 0.f}, sD[4] = {0.f, 0.f, 0.f, 0.f};
#pragma unroll
    for (int nt = 0; nt < 8; ++nt) {
        int col = nt * 16 + lm;
        float wa = aws[col], wd = awd[col];
#pragma unroll
        for (int r = 0; r < 4; ++r) {
            float v = acc[nt][r];
            h[(size_t)(m0 + lq * 4 + r) * OUT_DIM + col] = __float2half(v);
            sS[r] += v * wa;
            sD[r] += v * wd;
        }
    }
#pragma unroll
    for (int o = 1; o < 16; o <<= 1) {
#pragma unroll
        for (int r = 0; r < 4; ++r) {
            sS[r] += __shfl_xor(sS[r], o);
            sD[r] += __shfl_xor(sD[r], o);
        }
    }
    if (lm == 0) {
#pragma unroll
        for (int r = 0; r < 4; ++r) {
            int row = m0 + lq * 4 + r;
            as2[row] = sS[r];
            ad2[row] = sD[r];
        }
    }
}

// ================= fused softmax + aggregate, layer 1 =================
// wave per node (4 nodes / 256-block). Lane owns feats 4*lane..4*lane+3 (one head).
// No segment-max: logits are O(+-7), exp is safe in fp32, ratios unchanged.
__global__ __launch_bounds__(256) void aggregate1_fused(
        const int* __restrict__ rp, const int* __restrict__ cs,
        const __half* __restrict__ h1h, const float* __restrict__ as1,
        const float* __restrict__ ad1, const float* __restrict__ b1,
        __half* __restrict__ out1h) {
    __shared__ float salpha[4][64][4];   // [wave][edge-in-chunk][head]
    const int wv = threadIdx.x >> 6, lane = threadIdx.x & 63;
    const int d = blockIdx.x * 4 + wv;
    const int e0 = rp[d], deg = rp[d + 1] - e0;   // deg >= 1 (self-loop)
    const float4 adv = ((const float4*)ad1)[d];
    const int hd = lane >> 4;            // head of this lane's 4 feats
    const char* hbase = (const char*)h1h;
    const int lbyte = lane * 8;          // byte offset of lane's 4 fp16 feats in a row
    float* arow = &salpha[wv][0][0];
    float4 acc = make_float4(0.f, 0.f, 0.f, 0.f);
    float4 dsum = make_float4(0.f, 0.f, 0.f, 0.f);
    for (int c0 = 0; c0 < deg; c0 += 64) {
        const int clen = min(64, deg - c0);
        // --- stage this chunk: one edge per lane ---
        int idx = c0 + lane;
        bool valid = idx < deg;
        int s = valid ? cs[e0 + idx] : 0;
        float4 av = ((const float4*)as1)[s];
        float x0 = valid ? expf(leaky(av.x + adv.x)) : 0.f;
        float x1 = valid ? expf(leaky(av.y + adv.y)) : 0.f;
        float x2 = valid ? expf(leaky(av.z + adv.z)) : 0.f;
        float x3 = valid ? expf(leaky(av.w + adv.w)) : 0.f;
        *(float4*)(arow + lane * 4) = make_float4(x0, x1, x2, x3);
        dsum.x += x0; dsum.y += x1; dsum.z += x2; dsum.w += x3;
        int sreg = s << 9;               // byte offset of row s (256 fp16 = 512 B)
        __builtin_amdgcn_wave_barrier(); // keep ds_writes before ds_reads (same wave, DS in-order)
        // --- gather + accumulate ---
        int j = 0;
        for (; j + 4 <= clen; j += 4) {
            int o0 = __builtin_amdgcn_readlane(sreg, j);
            int o1 = __builtin_amdgcn_readlane(sreg, j + 1);
            int o2 = __builtin_amdgcn_readlane(sreg, j + 2);
            int o3 = __builtin_amdgcn_readlane(sreg, j + 3);
            h4 v0 = *(const h4*)(hbase + o0 + lbyte);
            h4 v1 = *(const h4*)(hbase + o1 + lbyte);
            h4 v2 = *(const h4*)(hbase + o2 + lbyte);
            h4 v3 = *(const h4*)(hbase + o3 + lbyte);
            float w0 = arow[(j + 0) * 4 + hd];
            float w1 = arow[(j + 1) * 4 + hd];
            float w2 = arow[(j + 2) * 4 + hd];
            float w3 = arow[(j + 3) * 4 + hd];
            acc.x += (float)v0[0] * w0; acc.y += (float)v0[1] * w0;
            acc.z += (float)v0[2] * w0; acc.w += (float)v0[3] * w0;
            acc.x += (float)v1[0] * w1; acc.y += (float)v1[1] * w1;
            acc.z += (float)v1[2] * w1; acc.w += (float)v1[3] * w1;
            acc.x += (float)v2[0] * w2; acc.y += (float)v2[1] * w2;
            acc.z += (float)v2[2] * w2; acc.w += (float)v2[3] * w2;
            acc.x += (float)v3[0] * w3; acc.y += (float)v3[1] * w3;
            acc.z += (float)v3[2] * w3; acc.w += (float)v3[3] * w3;
        }
        for (; j < clen; ++j) {
            int o0 = __builtin_amdgcn_readlane(sreg, j);
            h4 v0 = *(const h4*)(hbase + o0 + lbyte);
            float w0 = arow[j * 4 + hd];
            acc.x += (float)v0[0] * w0; acc.y += (float)v0[1] * w0;
            acc.z += (float)v0[2] * w0; acc.w += (float)v0[3] * w0;
        }
        __builtin_amdgcn_wave_barrier(); // next chunk's writes stay after these reads
    }
    // wave-reduce denominators (all 4 heads)
#pragma unroll
    for (int o = 32; o > 0; o >>= 1) {
        dsum.x += __shfl_xor(dsum.x, o); dsum.y += __shfl_xor(dsum.y, o);
        dsum.z += __shfl_xor(dsum.z, o); dsum.w += __shfl_xor(dsum.w, o);
    }
    float den = (hd == 0) ? dsum.x : (hd == 1) ? dsum.y : (hd == 2) ? dsum.z : dsum.w;
    float inv = 1.0f / (den + 1e-16f);
    float4 bv = ((const float4*)b1)[lane];
    float r0 = elu(acc.x * inv + bv.x);
    float r1 = elu(acc.y * inv + bv.y);
    float r2 = elu(acc.z * inv + bv.z);
    float r3 = elu(acc.w * inv + bv.w);
    h4 o;
    o[0] = (_Float16)r0; o[1] = (_Float16)r1; o[2] = (_Float16)r2; o[3] = (_Float16)r3;
    *(h4*)((char*)out1h + (size_t)d * 512 + lbyte) = o;
}

// ================= fused softmax + aggregate + bias + L2-normalize, layer 2 =================
// wave per node; lane owns feats 2*lane, 2*lane+1. Alphas via readlane (no LDS).
__global__ __launch_bounds__(256) void aggregate2_fused(
        const int* __restrict__ rp, const int* __restrict__ cs,
        const __half* __restrict__ h2h, const float* __restrict__ as2,
        const float* __restrict__ ad2, const float* __restrict__ b2,
        float* __restrict__ out) {
    const int wv = threadIdx.x >> 6, lane = threadIdx.x & 63;
    const int d = blockIdx.x * 4 + wv;
    const int e0 = rp[d], deg = rp[d + 1] - e0;
    const float adv = ad2[d];
    const char* hbase = (const char*)h2h;
    const int lbyte = lane * 4;          // 2 fp16 feats
    float2 acc = make_float2(0.f, 0.f);
    float dsum = 0.f;
    for (int c0 = 0; c0 < deg; c0 += 64) {
        const int clen = min(64, deg - c0);
        int idx = c0 + lane;
        bool valid = idx < deg;
        int s = valid ? cs[e0 + idx] : 0;
        float x = valid ? expf(leaky(as2[s] + adv)) : 0.f;
        dsum += x;
        int sreg = s << 8;               // 128 fp16 = 256 B per row
        int j = 0;
        for (; j + 4 <= clen; j += 4) {
            int o0 = __builtin_amdgcn_readlane(sreg, j);
            int o1 = __builtin_amdgcn_readlane(sreg, j + 1);
            int o2 = __builtin_amdgcn_readlane(sreg, j + 2);
            int o3 = __builtin_amdgcn_readlane(sreg, j + 3);
            float w0 = rl_f(x, j), w1 = rl_f(x, j + 1), w2 = rl_f(x, j + 2), w3 = rl_f(x, j + 3);
            __half2 v0 = *(const __half2*)(hbase + o0 + lbyte);
            __half2 v1 = *(const __half2*)(hbase + o1 + lbyte);
            __half2 v2 = *(const __half2*)(hbase + o2 + lbyte);
            __half2 v3 = *(const __half2*)(hbase + o3 + lbyte);
            float2 f;
            f = __half22float2(v0); acc.x += f.x * w0; acc.y += f.y * w0;
            f = __half22float2(v1); acc.x += f.x * w1; acc.y += f.y * w1;
            f = __half22float2(v2); acc.x += f.x * w2; acc.y += f.y * w2;
            f = __half22float2(v3); acc.x += f.x * w3; acc.y += f.y * w3;
        }
        for (; j < clen; ++j) {
            int o0 = __builtin_amdgcn_readlane(sreg, j);
            float w0 = rl_f(x, j);
            __half2 v0 = *(const __half2*)(hbase + o0 + lbyte);
            float2 f = __half22float2(v0);
            acc.x += f.x * w0; acc.y += f.y * w0;
        }
    }
#pragma unroll
    for (int o = 32; o > 0; o >>= 1) dsum += __shfl_xor(dsum, o);
    float inv = 1.0f / (dsum + 1e-16f);
    float2 bv = ((const float2*)b2)[lane];
    float vx = acc.x * inv + bv.x;
    float vy = acc.y * inv + bv.y;
    float ss = vx * vx + vy * vy;
#pragma unroll
    for (int o = 32; o > 0; o >>= 1) ss += __shfl_xor(ss, o);
    float sc = 1.0f / fmaxf(sqrtf(ss), 1e-12f);
    ((float2*)out)[(size_t)d * 64 + lane] = make_float2(vx * sc, vy * sc);
}

extern "C" void kernel_launch(void* const* d_in, const int* in_sizes, int n_in,
                              void* d_out, int out_size, void* d_ws, size_t ws_size,
                              hipStream_t stream) {
    const float* x     = (const float*)d_in[0];
    const int*   edge  = (const int*)d_in[1];
    const int*   src   = edge;
    const int*   dst   = edge + N_EDGES;
    const float* W1    = (const float*)d_in[2];
    const float* aw_s1 = (const float*)d_in[3];
    const float* aw_d1 = (const float*)d_in[4];
    const float* b1    = (const float*)d_in[5];
    const float* W2    = (const float*)d_in[6];
    const float* aw_s2 = (const float*)d_in[7];
    const float* aw_d2 = (const float*)d_in[8];
    const float* b2    = (const float*)d_in[9];
    float* out = (float*)d_out;

    // ---- workspace layout: small control buffers first, big streams last ----
    char* ws = (char*)d_ws;
    size_t off = 0;
    auto alloc = [&](size_t bytes) {
        void* p = ws + off;
        off += (bytes + 255) & ~(size_t)255;
        return p;
    };
    int*    col_src = (int*)alloc((size_t)ET * 4);                  // 3.4 MB
    int*    rp     = (int*)alloc((size_t)(N_NODES + 1) * 4);
    int*    cursor = (int*)alloc((size_t)N_NODES * 4);
    int*    cnt    = (int*)alloc((size_t)N_NODES * 4);
    int*    lscan  = (int*)alloc((size_t)NSCB * SCAN_B * 4);
    int*    bsum   = (int*)alloc((size_t)NSCB * 4);
    float*  as1    = (float*)alloc((size_t)N_NODES * HEADS * 4);
    float*  ad1    = (float*)alloc((size_t)N_NODES * HEADS * 4);
    float*  as2    = (float*)alloc((size_t)N_NODES * 4);
    float*  ad2    = (float*)alloc((size_t)N_NODES * 4);
    __half* w1t    = (__half*)alloc((size_t)IN_DIM * C1 * 2);
    __half* w2t    = (__half*)alloc((size_t)C1 * OUT_DIM * 2);
    __half* xh     = (__half*)alloc((size_t)N_NODES * IN_DIM * 2);  // 12.8 MB
    __half* h1h    = (__half*)alloc((size_t)N_NODES * C1 * 2);      // 25.6 MB (reused as h2h)
    __half* out1h  = (__half*)alloc((size_t)N_NODES * C1 * 2);      // 25.6 MB
    __half* h2h    = h1h;  // layer-1 projection dead after aggregate1
    const size_t ws_used = off;

    // Reproduce call-1 initial state every call (harness re-poisons ws/out with 0xAA).
    hipMemsetAsync(d_ws, 0, ws_used, stream);
    hipMemsetAsync(d_out, 0, (size_t)out_size * 4, stream);

    const int egrid = (ET + 255) / 256;

    // ---- prep + CSR build ----
    convert_x<<<2048, 256, 0, stream>>>(x, xh);
    prep_weights<<<128, 256, 0, stream>>>(W1, W2, w1t, w2t);
    count_kernel<<<egrid, 256, 0, stream>>>(dst, cnt);
    scan_local<<<NSCB, SCAN_B, 0, stream>>>(cnt, lscan, bsum);
    scan_bsum<<<1, 64, 0, stream>>>(bsum);
    scan_final<<<NSCB, SCAN_B, 0, stream>>>(cnt, lscan, bsum, rp, cursor);
    scatter_kernel<<<egrid, 256, 0, stream>>>(src, dst, cursor, col_src);

    // ---- layer 1 ----
    gemm1_mfma<<<(MTILES + 3) / 4, 256, 0, stream>>>(xh, w1t, aw_s1, aw_d1, h1h, as1, ad1);
    aggregate1_fused<<<N_NODES / 4, 256, 0, stream>>>(rp, col_src, h1h, as1, ad1, b1, out1h);

    // ---- layer 2 ----
    gemm2_mfma<<<(MTILES + 3) / 4, 256, 0, stream>>>(out1h, w2t, aw_s2, aw_d2, h2h, as2, ad2);
    aggregate2_fused<<<N_NODES / 4, 256, 0, stream>>>(rp, col_src, h2h, as2, ad2, b2, out);
}

// Round 7
// 370.984 us; speedup vs baseline: 4.7210x; 1.0344x over previous
//
#include <hip/hip_runtime.h>
#include <hip/hip_fp16.h>
#include <math.h>

#define N_NODES 50000
#define N_EDGES 800000
#define ET (N_EDGES + N_NODES)   // edges + self-loops
#define IN_DIM 128
#define HID 64
#define HEADS 4
#define C1 (HEADS * HID)         // 256
#define OUT_DIM 128
#define NEG_SLOPE 0.2f
#define MTILES 3125              // 50000 / 16 row-tiles
#define SCAN_B 1024
#define NSCB 49                  // ceil(50000/1024)

typedef _Float16 h8 __attribute__((ext_vector_type(8)));
typedef float f4 __attribute__((ext_vector_type(4)));

__device__ __forceinline__ float leaky(float v) { return v > 0.0f ? v : NEG_SLOPE * v; }
__device__ __forceinline__ float elu(float v) { return v > 0.0f ? v : expm1f(v); }

// ================= fused prep: x->fp16, weight transpose->fp16, dst histogram =================
__global__ void prep_kernel(const float* __restrict__ x, const float* __restrict__ W1,
                            const float* __restrict__ W2, const int* __restrict__ dst,
                            __half* __restrict__ xh, __half* __restrict__ w1t,
                            __half* __restrict__ w2t, int* __restrict__ cnt) {
    const int tid = blockIdx.x * blockDim.x + threadIdx.x;
    const int np = gridDim.x * blockDim.x;
    for (int i = tid; i < N_NODES * IN_DIM / 4; i += np) {
        float4 v = ((const float4*)x)[i];
        ((__half2*)xh)[2 * i]     = __floats2half2_rn(v.x, v.y);
        ((__half2*)xh)[2 * i + 1] = __floats2half2_rn(v.z, v.w);
    }
    for (int i = tid; i < IN_DIM * C1; i += np) {
        int k1 = i >> 8, n1 = i & 255;
        w1t[n1 * IN_DIM + k1] = __float2half(W1[i]);
        int k2 = i >> 7, n2 = i & 127;
        w2t[n2 * C1 + k2] = __float2half(W2[i]);
    }
    for (int i = tid; i < ET; i += np) {
        int d = (i < N_EDGES) ? dst[i] : i - N_EDGES;
        atomicAdd(&cnt[d], 1);
    }
}

// ================= CSR scan + scatter =================
__global__ void scan_local(const int* __restrict__ cnt, int* __restrict__ lscan,
                           int* __restrict__ bsum) {
    __shared__ int wsum[16];
    const int t = threadIdx.x, lane = t & 63, wv = t >> 6;
    int idx = blockIdx.x * SCAN_B + t;
    int v = (idx < N_NODES) ? cnt[idx] : 0;
    int sc = v;
#pragma unroll
    for (int o = 1; o < 64; o <<= 1) {
        int u = __shfl_up(sc, o);
        if (lane >= o) sc += u;
    }
    if (lane == 63) wsum[wv] = sc;
    __syncthreads();
    if (t == 0) {
        int run = 0;
#pragma unroll
        for (int w = 0; w < 16; ++w) { int s = wsum[w]; wsum[w] = run; run += s; }
        bsum[blockIdx.x] = run;
    }
    __syncthreads();
    if (idx < N_NODES) lscan[idx] = sc + wsum[wv];  // inclusive within block
}

__global__ void scan_bsum(int* __restrict__ bsum) {  // 1 block, 64 thr
    const int t = threadIdx.x;
    int v = (t < NSCB) ? bsum[t] : 0;
    int sc = v;
#pragma unroll
    for (int o = 1; o < 64; o <<= 1) {
        int u = __shfl_up(sc, o);
        if (t >= o) sc += u;
    }
    if (t < NSCB) bsum[t] = sc - v;  // exclusive
}

__global__ void scan_final(const int* __restrict__ cnt, const int* __restrict__ lscan,
                           const int* __restrict__ bsum, int* __restrict__ rp,
                           int* __restrict__ cursor) {
    int idx = blockIdx.x * SCAN_B + threadIdx.x;
    if (idx == 0) rp[0] = 0;
    if (idx >= N_NODES) return;
    int inc = lscan[idx] + bsum[idx >> 10];
    rp[idx + 1] = inc;
    cursor[idx] = inc - cnt[idx];
}

__global__ void scatter_kernel(const int* __restrict__ src, const int* __restrict__ dst,
                               int* __restrict__ cursor, int* __restrict__ col_src) {
    int i = blockIdx.x * blockDim.x + threadIdx.x;
    if (i >= ET) return;
    int s, d;
    if (i < N_EDGES) { s = src[i]; d = dst[i]; } else { s = d = i - N_EDGES; }
    int pos = atomicAdd(&cursor[d], 1);
    col_src[pos] = s;
}

// ================= GEMM1 (MFMA fp16) + fused attention dots =================
__global__ __launch_bounds__(256) void gemm1_mfma(
        const __half* __restrict__ xh, const __half* __restrict__ w1t,
        const float* __restrict__ aws, const float* __restrict__ awd,
        __half* __restrict__ h, float* __restrict__ as1, float* __restrict__ ad1) {
    const int tile = blockIdx.x * 4 + (threadIdx.x >> 6);
    if (tile >= MTILES) return;
    const int lane = threadIdx.x & 63;
    const int m0 = tile * 16, lm = lane & 15, lq = lane >> 4;
    h8 afrag[4];
    const h8* arow = (const h8*)(xh + (size_t)(m0 + lm) * IN_DIM + lq * 8);
#pragma unroll
    for (int kt = 0; kt < 4; ++kt) afrag[kt] = arow[kt * 4];
    f4 acc[16];
#pragma unroll
    for (int nt = 0; nt < 16; ++nt) acc[nt] = (f4){0.f, 0.f, 0.f, 0.f};
#pragma unroll
    for (int nt = 0; nt < 16; ++nt) {
        const h8* brow = (const h8*)(w1t + (size_t)(nt * 16 + lm) * IN_DIM + lq * 8);
#pragma unroll
        for (int kt = 0; kt < 4; ++kt)
            acc[nt] = __builtin_amdgcn_mfma_f32_16x16x32_f16(afrag[kt], brow[kt * 4],
                                                             acc[nt], 0, 0, 0);
    }
    float sS[4][4] = {{0.f}}, sD[4][4] = {{0.f}};
#pragma unroll
    for (int nt = 0; nt < 16; ++nt) {
        int col = nt * 16 + lm;
        float wa = aws[col], wd = awd[col];
        int hd = nt >> 2;
#pragma unroll
        for (int r = 0; r < 4; ++r) {
            float v = acc[nt][r];
            h[(size_t)(m0 + lq * 4 + r) * C1 + col] = __float2half(v);
            sS[hd][r] += v * wa;
            sD[hd][r] += v * wd;
        }
    }
#pragma unroll
    for (int o = 1; o < 16; o <<= 1) {
#pragma unroll
        for (int hd = 0; hd < 4; ++hd)
#pragma unroll
            for (int r = 0; r < 4; ++r) {
                sS[hd][r] += __shfl_xor(sS[hd][r], o);
                sD[hd][r] += __shfl_xor(sD[hd][r], o);
            }
    }
    if (lm == 0) {
#pragma unroll
        for (int r = 0; r < 4; ++r) {
            int row = m0 + lq * 4 + r;
            ((float4*)as1)[row] = make_float4(sS[0][r], sS[1][r], sS[2][r], sS[3][r]);
            ((float4*)ad1)[row] = make_float4(sD[0][r], sD[1][r], sD[2][r], sD[3][r]);
        }
    }
}

// ================= GEMM2 (MFMA fp16) + fused attention dots (1 head) =================
__global__ __launch_bounds__(256) void gemm2_mfma(
        const __half* __restrict__ ah, const __half* __restrict__ w2t,
        const float* __restrict__ aws, const float* __restrict__ awd,
        __half* __restrict__ h, float* __restrict__ as2, float* __restrict__ ad2) {
    const int tile = blockIdx.x * 4 + (threadIdx.x >> 6);
    if (tile >= MTILES) return;
    const int lane = threadIdx.x & 63;
    const int m0 = tile * 16, lm = lane & 15, lq = lane >> 4;
    h8 afrag[8];
    const h8* arow = (const h8*)(ah + (size_t)(m0 + lm) * C1 + lq * 8);
#pragma unroll
    for (int kt = 0; kt < 8; ++kt) afrag[kt] = arow[kt * 4];
    f4 acc[8];
#pragma unroll
    for (int nt = 0; nt < 8; ++nt) acc[nt] = (f4){0.f, 0.f, 0.f, 0.f};
#pragma unroll
    for (int nt = 0; nt < 8; ++nt) {
        const h8* brow = (const h8*)(w2t + (size_t)(nt * 16 + lm) * C1 + lq * 8);
#pragma unroll
        for (int kt = 0; kt < 8; ++kt)
            acc[nt] = __builtin_amdgcn_mfma_f32_16x16x32_f16(afrag[kt], brow[kt * 4],
                                                             acc[nt], 0, 0, 0);
    }
    float sS[4] = {0.f, 0.f, 0.f, 0.f}, sD[4] = {0.f, 0.f, 0.f, 0.f};
#pragma unroll
    for (int nt = 0; nt < 8; ++nt) {
        int col = nt * 16 + lm;
        float wa = aws[col], wd = awd[col];
#pragma unroll
        for (int r = 0; r < 4; ++r) {
            float v = acc[nt][r];
            h[(size_t)(m0 + lq * 4 + r) * OUT_DIM + col] = __float2half(v);
            sS[r] += v * wa;
            sD[r] += v * wd;
        }
    }
#pragma unroll
    for (int o = 1; o < 16; o <<= 1) {
#pragma unroll
        for (int r = 0; r < 4; ++r) {
            sS[r] += __shfl_xor(sS[r], o);
            sD[r] += __shfl_xor(sD[r], o);
        }
    }
    if (lm == 0) {
#pragma unroll
        for (int r = 0; r < 4; ++r) {
            int row = m0 + lq * 4 + r;
            as2[row] = sS[r];
            ad2[row] = sD[r];
        }
    }
}

// ================= fused softmax + aggregate, layer 1 =================
// wave per node; 2 rows per dwordx4 load: lanes 0-31 even edge, 32-63 odd edge,
// each lane owns 8 contiguous feats (16 B). LDS stages {row_byte_off, alpha} pairs.
__global__ __launch_bounds__(256) void aggregate1_fused(
        const int* __restrict__ rp, const int* __restrict__ cs,
        const __half* __restrict__ h1h, const float* __restrict__ as1,
        const float* __restrict__ ad1, const float* __restrict__ b1,
        __half* __restrict__ out1h) {
    __shared__ int2 stg[4][64][4];   // [wave][edge][head] = {row byte offset, alpha bits}
    const int wv = threadIdx.x >> 6, lane = threadIdx.x & 63;
    const int d = blockIdx.x * 4 + wv;
    const int e0 = rp[d], deg = rp[d + 1] - e0;  // deg >= 1 (self-loop)
    const float4 adv = ((const float4*)ad1)[d];
    const int half = lane >> 5, li = lane & 31;
    const int head = li >> 3;        // feats [li*8, li*8+8) all in head li>>3
    const int lbyte = li * 16;       // 8 fp16 = 16 B
    const char* hbase = (const char*)h1h;
    int2* sp = &stg[wv][0][0];
    float acc[8] = {0.f, 0.f, 0.f, 0.f, 0.f, 0.f, 0.f, 0.f};
    float4 dsum = make_float4(0.f, 0.f, 0.f, 0.f);
    for (int c0 = 0; c0 < deg; c0 += 64) {
        const int clen = min(64, deg - c0);
        int idx = c0 + lane;
        bool valid = idx < deg;
        int s = valid ? cs[e0 + idx] : 0;
        float4 av = ((const float4*)as1)[s];
        float x0 = valid ? expf(leaky(av.x + adv.x)) : 0.f;
        float x1 = valid ? expf(leaky(av.y + adv.y)) : 0.f;
        float x2 = valid ? expf(leaky(av.z + adv.z)) : 0.f;
        float x3 = valid ? expf(leaky(av.w + adv.w)) : 0.f;
        int off = valid ? (s << 9) : 0;   // row = 256 fp16 = 512 B
        ((int4*)sp)[lane * 2]     = make_int4(off, __float_as_int(x0), off, __float_as_int(x1));
        ((int4*)sp)[lane * 2 + 1] = make_int4(off, __float_as_int(x2), off, __float_as_int(x3));
        dsum.x += x0; dsum.y += x1; dsum.z += x2; dsum.w += x3;
        __builtin_amdgcn_wave_barrier();  // DS in-order per wave; block compiler reordering
        int j = 0;
        for (; j + 4 <= clen; j += 4) {
            int2 p0 = sp[(j + half) * 4 + head];
            int2 p1 = sp[(j + 2 + half) * 4 + head];
            h8 v0 = *(const h8*)(hbase + p0.x + lbyte);
            h8 v1 = *(const h8*)(hbase + p1.x + lbyte);
            float w0 = __int_as_float(p0.y), w1 = __int_as_float(p1.y);
#pragma unroll
            for (int f = 0; f < 8; ++f) acc[f] += (float)v0[f] * w0;
#pragma unroll
            for (int f = 0; f < 8; ++f) acc[f] += (float)v1[f] * w1;
        }
        for (; j < clen; j += 2) {
            int2 p0 = sp[(j + half) * 4 + head];
            h8 v0 = *(const h8*)(hbase + p0.x + lbyte);
            float w0 = __int_as_float(p0.y);
#pragma unroll
            for (int f = 0; f < 8; ++f) acc[f] += (float)v0[f] * w0;
        }
        __builtin_amdgcn_wave_barrier();
    }
    // combine even/odd halves (lane l + lane l^32 hold same feats)
#pragma unroll
    for (int f = 0; f < 8; ++f) acc[f] += __shfl_xor(acc[f], 32);
    // denominators over all 64 lanes
#pragma unroll
    for (int o = 32; o > 0; o >>= 1) {
        dsum.x += __shfl_xor(dsum.x, o); dsum.y += __shfl_xor(dsum.y, o);
        dsum.z += __shfl_xor(dsum.z, o); dsum.w += __shfl_xor(dsum.w, o);
    }
    float den = (head == 0) ? dsum.x : (head == 1) ? dsum.y : (head == 2) ? dsum.z : dsum.w;
    if (half == 0) {
        float inv = 1.0f / (den + 1e-16f);
        float4 bA = ((const float4*)b1)[li * 2];
        float4 bB = ((const float4*)b1)[li * 2 + 1];
        h8 o;
        o[0] = (_Float16)elu(acc[0] * inv + bA.x);
        o[1] = (_Float16)elu(acc[1] * inv + bA.y);
        o[2] = (_Float16)elu(acc[2] * inv + bA.z);
        o[3] = (_Float16)elu(acc[3] * inv + bA.w);
        o[4] = (_Float16)elu(acc[4] * inv + bB.x);
        o[5] = (_Float16)elu(acc[5] * inv + bB.y);
        o[6] = (_Float16)elu(acc[6] * inv + bB.z);
        o[7] = (_Float16)elu(acc[7] * inv + bB.w);
        *(h8*)((char*)out1h + (size_t)d * 512 + lbyte) = o;
    }
}

// ================= fused softmax + aggregate + bias + L2-normalize, layer 2 =================
// wave per node; 4 rows per dwordx4 load: lane group q = lane>>4 handles edge j+q,
// 16 lanes per row, 8 feats (16 B) per lane.
__global__ __launch_bounds__(256) void aggregate2_fused(
        const int* __restrict__ rp, const int* __restrict__ cs,
        const __half* __restrict__ h2h, const float* __restrict__ as2,
        const float* __restrict__ ad2, const float* __restrict__ b2,
        float* __restrict__ out) {
    __shared__ int2 stg[4][64];      // [wave][edge] = {row byte offset, alpha bits}
    const int wv = threadIdx.x >> 6, lane = threadIdx.x & 63;
    const int d = blockIdx.x * 4 + wv;
    const int e0 = rp[d], deg = rp[d + 1] - e0;
    const float adv = ad2[d];
    const int q = lane >> 4, li = lane & 15;
    const int lbyte = li * 16;       // 8 fp16
    const char* hbase = (const char*)h2h;
    float acc[8] = {0.f, 0.f, 0.f, 0.f, 0.f, 0.f, 0.f, 0.f};
    float dsum = 0.f;
    for (int c0 = 0; c0 < deg; c0 += 64) {
        const int clen = min(64, deg - c0);
        int idx = c0 + lane;
        bool valid = idx < deg;
        int s = valid ? cs[e0 + idx] : 0;
        float x = valid ? expf(leaky(as2[s] + adv)) : 0.f;
        stg[wv][lane] = make_int2(valid ? (s << 8) : 0, __float_as_int(x));  // row = 256 B
        dsum += x;
        __builtin_amdgcn_wave_barrier();
        int j = 0;
        for (; j + 8 <= clen; j += 8) {
            int2 p0 = stg[wv][j + q];
            int2 p1 = stg[wv][j + 4 + q];
            h8 v0 = *(const h8*)(hbase + p0.x + lbyte);
            h8 v1 = *(const h8*)(hbase + p1.x + lbyte);
            float w0 = __int_as_float(p0.y), w1 = __int_as_float(p1.y);
#pragma unroll
            for (int f = 0; f < 8; ++f) acc[f] += (float)v0[f] * w0;
#pragma unroll
            for (int f = 0; f < 8; ++f) acc[f] += (float)v1[f] * w1;
        }
        for (; j < clen; j += 4) {
            int2 p0 = stg[wv][j + q];
            h8 v0 = *(const h8*)(hbase + p0.x + lbyte);
            float w0 = __int_as_float(p0.y);
#pragma unroll
            for (int f = 0; f < 8; ++f) acc[f] += (float)v0[f] * w0;
        }
        __builtin_amdgcn_wave_barrier();
    }
#pragma unroll
    for (int f = 0; f < 8; ++f) {
        acc[f] += __shfl_xor(acc[f], 16);
        acc[f] += __shfl_xor(acc[f], 32);
    }
#pragma unroll
    for (int o = 32; o > 0; o >>= 1) dsum += __shfl_xor(dsum, o);
    if (q == 0) {
        float inv = 1.0f / (dsum + 1e-16f);
        float4 bA = ((const float4*)b2)[li * 2];
        float4 bB = ((const float4*)b2)[li * 2 + 1];
        float v0 = acc[0] * inv + bA.x, v1 = acc[1] * inv + bA.y;
        float v2 = acc[2] * inv + bA.z, v3 = acc[3] * inv + bA.w;
        float v4 = acc[4] * inv + bB.x, v5 = acc[5] * inv + bB.y;
        float v6 = acc[6] * inv + bB.z, v7 = acc[7] * inv + bB.w;
        float ss = v0 * v0 + v1 * v1 + v2 * v2 + v3 * v3 +
                   v4 * v4 + v5 * v5 + v6 * v6 + v7 * v7;
#pragma unroll
        for (int o = 1; o < 16; o <<= 1) ss += __shfl_xor(ss, o);  // lanes 0-15 group
        float sc = 1.0f / fmaxf(sqrtf(ss), 1e-12f);
        float4* orow = (float4*)((char*)out + (size_t)d * 512 + li * 32);
        orow[0] = make_float4(v0 * sc, v1 * sc, v2 * sc, v3 * sc);
        orow[1] = make_float4(v4 * sc, v5 * sc, v6 * sc, v7 * sc);
    }
}

extern "C" void kernel_launch(void* const* d_in, const int* in_sizes, int n_in,
                              void* d_out, int out_size, void* d_ws, size_t ws_size,
                              hipStream_t stream) {
    const float* x     = (const float*)d_in[0];
    const int*   edge  = (const int*)d_in[1];
    const int*   src   = edge;
    const int*   dst   = edge + N_EDGES;
    const float* W1    = (const float*)d_in[2];
    const float* aw_s1 = (const float*)d_in[3];
    const float* aw_d1 = (const float*)d_in[4];
    const float* b1    = (const float*)d_in[5];
    const float* W2    = (const float*)d_in[6];
    const float* aw_s2 = (const float*)d_in[7];
    const float* aw_d2 = (const float*)d_in[8];
    const float* b2    = (const float*)d_in[9];
    float* out = (float*)d_out;

    // ---- workspace layout: small control buffers first, big streams last ----
    char* ws = (char*)d_ws;
    size_t off = 0;
    auto alloc = [&](size_t bytes) {
        void* p = ws + off;
        off += (bytes + 255) & ~(size_t)255;
        return p;
    };
    int*    col_src = (int*)alloc((size_t)ET * 4);                  // 3.4 MB
    int*    rp     = (int*)alloc((size_t)(N_NODES + 1) * 4);
    int*    cursor = (int*)alloc((size_t)N_NODES * 4);
    int*    cnt    = (int*)alloc((size_t)N_NODES * 4);
    int*    lscan  = (int*)alloc((size_t)NSCB * SCAN_B * 4);
    int*    bsum   = (int*)alloc((size_t)NSCB * 4);
    float*  as1    = (float*)alloc((size_t)N_NODES * HEADS * 4);
    float*  ad1    = (float*)alloc((size_t)N_NODES * HEADS * 4);
    float*  as2    = (float*)alloc((size_t)N_NODES * 4);
    float*  ad2    = (float*)alloc((size_t)N_NODES * 4);
    __half* w1t    = (__half*)alloc((size_t)IN_DIM * C1 * 2);
    __half* w2t    = (__half*)alloc((size_t)C1 * OUT_DIM * 2);
    __half* xh     = (__half*)alloc((size_t)N_NODES * IN_DIM * 2);  // 12.8 MB
    __half* h1h    = (__half*)alloc((size_t)N_NODES * C1 * 2);      // 25.6 MB (reused as h2h)
    __half* out1h  = (__half*)alloc((size_t)N_NODES * C1 * 2);      // 25.6 MB
    __half* h2h    = h1h;  // layer-1 projection dead after aggregate1
    const size_t ws_used = off;

    // Reproduce call-1 initial state every call (harness re-poisons ws with 0xAA).
    // d_out needs no zeroing: aggregate2 fully writes it.
    hipMemsetAsync(d_ws, 0, ws_used, stream);

    const int egrid = (ET + 255) / 256;

    // ---- prep (x->fp16 + weight transpose + histogram) + CSR build ----
    prep_kernel<<<2048, 256, 0, stream>>>(x, W1, W2, dst, xh, w1t, w2t, cnt);
    scan_local<<<NSCB, SCAN_B, 0, stream>>>(cnt, lscan, bsum);
    scan_bsum<<<1, 64, 0, stream>>>(bsum);
    scan_final<<<NSCB, SCAN_B, 0, stream>>>(cnt, lscan, bsum, rp, cursor);
    scatter_kernel<<<egrid, 256, 0, stream>>>(src, dst, cursor, col_src);

    // ---- layer 1 ----
    gemm1_mfma<<<(MTILES + 3) / 4, 256, 0, stream>>>(xh, w1t, aw_s1, aw_d1, h1h, as1, ad1);
    aggregate1_fused<<<N_NODES / 4, 256, 0, stream>>>(rp, col_src, h1h, as1, ad1, b1, out1h);

    // ---- layer 2 ----
    gemm2_mfma<<<(MTILES + 3) / 4, 256, 0, stream>>>(out1h, w2t, aw_s2, aw_d2, h2h, as2, ad2);
    aggregate2_fused<<<N_NODES / 4, 256, 0, stream>>>(rp, col_src, h2h, as2, ad2, b2, out);
}